// Round 1
// baseline (947.017 us; speedup 1.0000x reference)
//
#include <hip/hip_runtime.h>
#include <hip/hip_bf16.h>
#include <math.h>

#define N_PTS 8192
#define C_IN  256
#define OUT_C 256
#define NSAMP 16
#define H_W   32
#define EPSBN 1e-5f

// ---------------------------------------------------------------- prep
__global__ __launch_bounds__(256) void prep_kernel(
    const float* __restrict__ p,
    const float* __restrict__ wq, const float* __restrict__ wk, const float* __restrict__ wv,
    const float* __restrict__ bq, const float* __restrict__ bk, const float* __restrict__ bv,
    float4* __restrict__ p4, float* __restrict__ Wp, float* __restrict__ biasp) {
  int tid = blockIdx.x * blockDim.x + threadIdx.x;
  int total = 256 * 768;
  if (tid < total) {
    int k = tid / 768, m = tid % 768;
    float v;
    if (m < 256)      v = wq[k * 256 + m];
    else if (m < 512) v = wk[k * 256 + (m - 256)];
    else              v = wv[k * 256 + (m - 512)];
    Wp[tid] = v;
  }
  if (tid < 768) {
    biasp[tid] = tid < 256 ? bq[tid] : (tid < 512 ? bk[tid - 256] : bv[tid - 512]);
  }
  if (tid < N_PTS) {
    float x = p[tid * 3 + 0], y = p[tid * 3 + 1], z = p[tid * 3 + 2];
    float sq = x * x;
    sq += y * y;
    sq += z * z;
    p4[tid] = make_float4(x, y, z, sq);
  }
}

// ---------------------------------------------------------------- qkv gemm (fp32, 64x64x16 tiles)
__global__ __launch_bounds__(256) void gemm_qkv(
    const float* __restrict__ x, const float* __restrict__ Wp,
    const float* __restrict__ biasp, float* __restrict__ xqkv) {
  __shared__ float As[16][64];  // [k][m]
  __shared__ float Bs[16][64];  // [k][n]
  const int bm = blockIdx.x % (N_PTS / 64);
  const int bn = blockIdx.x / (N_PTS / 64);
  const int tid = threadIdx.x;
  const int tm = tid % 16, tn = tid / 16;
  const int ar = tid / 4, ac = tid % 4;   // A-load: row, col-quad
  const int br = tid / 16, bc = tid % 16; // B-load: row, col-quad

  float acc[4][4];
  #pragma unroll
  for (int i = 0; i < 4; ++i)
    #pragma unroll
    for (int j = 0; j < 4; ++j) acc[i][j] = 0.f;

  for (int k0 = 0; k0 < C_IN; k0 += 16) {
    float4 av = *(const float4*)&x[(size_t)(bm * 64 + ar) * C_IN + k0 + ac * 4];
    float4 bv = *(const float4*)&Wp[(size_t)(k0 + br) * 768 + bn * 64 + bc * 4];
    __syncthreads();
    As[ac * 4 + 0][ar] = av.x;
    As[ac * 4 + 1][ar] = av.y;
    As[ac * 4 + 2][ar] = av.z;
    As[ac * 4 + 3][ar] = av.w;
    *(float4*)&Bs[br][bc * 4] = bv;
    __syncthreads();
    #pragma unroll
    for (int kk = 0; kk < 16; ++kk) {
      float a0 = As[kk][tm * 4 + 0], a1 = As[kk][tm * 4 + 1];
      float a2 = As[kk][tm * 4 + 2], a3 = As[kk][tm * 4 + 3];
      float b0 = Bs[kk][tn * 4 + 0], b1 = Bs[kk][tn * 4 + 1];
      float b2 = Bs[kk][tn * 4 + 2], b3 = Bs[kk][tn * 4 + 3];
      acc[0][0] += a0 * b0; acc[0][1] += a0 * b1; acc[0][2] += a0 * b2; acc[0][3] += a0 * b3;
      acc[1][0] += a1 * b0; acc[1][1] += a1 * b1; acc[1][2] += a1 * b2; acc[1][3] += a1 * b3;
      acc[2][0] += a2 * b0; acc[2][1] += a2 * b1; acc[2][2] += a2 * b2; acc[2][3] += a2 * b3;
      acc[3][0] += a3 * b0; acc[3][1] += a3 * b1; acc[3][2] += a3 * b2; acc[3][3] += a3 * b3;
    }
  }
  const int col = bn * 64 + tn * 4;
  float4 b4 = *(const float4*)&biasp[col];
  #pragma unroll
  for (int i = 0; i < 4; ++i) {
    int row = bm * 64 + tm * 4 + i;
    float4 o;
    o.x = acc[i][0] + b4.x; o.y = acc[i][1] + b4.y;
    o.z = acc[i][2] + b4.z; o.w = acc[i][3] + b4.w;
    *(float4*)&xqkv[(size_t)row * 768 + col] = o;
  }
}

// ---------------------------------------------------------------- knn: per-thread sorted-16 u64-key chain
// key = (orderable(dist) << 32) | j  — exact fp32 ordering, index tie-break (matches stable top_k)
__device__ __forceinline__ unsigned long long make_key(float d, int j) {
  unsigned int di = __float_as_uint(d);
  unsigned int ord = ((int)di >= 0) ? (di ^ 0x80000000u) : ~di;
  return ((unsigned long long)ord << 32) | (unsigned int)j;
}

__device__ __forceinline__ void chain_insert(unsigned long long (&ak)[16], unsigned long long key) {
  if (key < ak[0]) {
    #pragma unroll
    for (int s = 0; s < 15; ++s) {
      unsigned long long mn = ak[s] < key ? ak[s] : key;   // min(old a_s, key)
      unsigned long long nx = ak[s + 1];                   // old a_{s+1}
      ak[s] = nx > mn ? nx : mn;                           // max(a_{s+1}, min(a_s, key))
    }
    ak[15] = ak[15] < key ? ak[15] : key;
  }
}

#define KNN_CHUNK 512
#define KNN_SPLIT (N_PTS / KNN_CHUNK)  // 16

__global__ __launch_bounds__(256) void knn_partial(
    const float4* __restrict__ p4, unsigned long long* __restrict__ partial) {
  const int pt = (blockIdx.x % (N_PTS / 256)) * 256 + threadIdx.x;
  const int chunk = blockIdx.x / (N_PTS / 256);
  const int j0 = chunk * KNN_CHUNK;
  const float4 pi = p4[pt];
  unsigned long long ak[16];
  #pragma unroll
  for (int s = 0; s < 16; ++s) ak[s] = ~0ULL;

  for (int j = j0; j < j0 + KNN_CHUNK; ++j) {
    float4 pj = p4[j];  // j uniform across wave -> scalar path
    float dot = pi.x * pj.x + pi.y * pj.y + pi.z * pj.z;
    float d = pi.w + pj.w - 2.0f * dot;
    chain_insert(ak, make_key(d, j));
  }
  unsigned long long* dst = &partial[(size_t)pt * (KNN_SPLIT * 16) + chunk * 16];
  #pragma unroll
  for (int s = 0; s < 16; ++s) dst[s] = ak[s];
}

__global__ __launch_bounds__(256) void knn_merge(
    const unsigned long long* __restrict__ partial, int* __restrict__ nbr) {
  const int pt = blockIdx.x * 256 + threadIdx.x;
  const unsigned long long* src = &partial[(size_t)pt * (KNN_SPLIT * 16)];
  unsigned long long ak[16];
  #pragma unroll
  for (int s = 0; s < 16; ++s) ak[s] = ~0ULL;
  for (int e = 0; e < KNN_SPLIT * 16; ++e) {
    chain_insert(ak, src[e]);
  }
  #pragma unroll
  for (int s = 0; s < 16; ++s) nbr[pt * NSAMP + s] = (int)(ak[s] & 0xFFFFFFFFu);
}

// ---------------------------------------------------------------- fused per-point transform
__global__ __launch_bounds__(256) void fused_pt(
    const float* __restrict__ p, const float* __restrict__ xqkv, const int* __restrict__ nbr,
    const float* __restrict__ pw1, const float* __restrict__ pb1,
    const float* __restrict__ pbng, const float* __restrict__ pbnb,
    const float* __restrict__ pbnm, const float* __restrict__ pbnv,
    const float* __restrict__ pw2, const float* __restrict__ pb2,
    const float* __restrict__ bn1g, const float* __restrict__ bn1b,
    const float* __restrict__ bn1m, const float* __restrict__ bn1v,
    const float* __restrict__ l1w, const float* __restrict__ l1b,
    const float* __restrict__ bn2g, const float* __restrict__ bn2b,
    const float* __restrict__ bn2m, const float* __restrict__ bn2v,
    const float* __restrict__ l2w, const float* __restrict__ l2b,
    float* __restrict__ out) {
  __shared__ float pr_s[NSAMP][OUT_C];   // 16 KB
  __shared__ float a_s[NSAMP][C_IN];     // 16 KB
  __shared__ float h1_s[NSAMP][H_W];     // 2 KB
  __shared__ float w_s[NSAMP][H_W];      // 2 KB
  __shared__ float q3_s[NSAMP][4];
  __shared__ int jn[NSAMP];

  const int i = blockIdx.x;
  const int tid = threadIdx.x;

  // stage 1: neighbor ids + linear_p first layer (3->3 + bn + relu)
  if (tid < NSAMP) {
    int j = nbr[i * NSAMP + tid];
    jn[tid] = j;
    float rx = p[j * 3 + 0] - p[i * 3 + 0];
    float ry = p[j * 3 + 1] - p[i * 3 + 1];
    float rz = p[j * 3 + 2] - p[i * 3 + 2];
    #pragma unroll
    for (int c3 = 0; c3 < 3; ++c3) {
      float t = rx * pw1[0 * 3 + c3] + ry * pw1[1 * 3 + c3] + rz * pw1[2 * 3 + c3] + pb1[c3];
      t = (t - pbnm[c3]) * rsqrtf(pbnv[c3] + EPSBN) * pbng[c3] + pbnb[c3];
      q3_s[tid][c3] = fmaxf(t, 0.f);
    }
  }
  __syncthreads();

  // stage 2: pr (3->256), r_qk, bn1+relu
  const int c = tid;
  const float xq_c = xqkv[(size_t)i * 768 + c];
  const float s1 = bn1g[c] * rsqrtf(bn1v[c] + EPSBN);
  const float o1 = bn1b[c] - bn1m[c] * s1;
  const float w2c0 = pw2[0 * 256 + c], w2c1 = pw2[256 + c], w2c2 = pw2[512 + c];
  const float pb2c = pb2[c];
  #pragma unroll
  for (int t = 0; t < NSAMP; ++t) {
    int j = jn[t];
    float prv = q3_s[t][0] * w2c0 + q3_s[t][1] * w2c1 + q3_s[t][2] * w2c2 + pb2c;
    pr_s[t][c] = prv;
    float xkv = xqkv[(size_t)j * 768 + 256 + c];
    float r = xkv - xq_c + prv;
    a_s[t][c] = fmaxf(r * s1 + o1, 0.f);
  }
  __syncthreads();

  // stage 3: linear_w l1 (256->32) + bn2 + relu
  #pragma unroll
  for (int pp = 0; pp < 2; ++pp) {
    int P = tid + pp * 256;
    int t = P >> 5, h = P & 31;
    float acc = l1b[h];
    const float* ar = a_s[t];
    #pragma unroll 4
    for (int cc = 0; cc < 256; cc += 4) {
      float4 a4 = *(const float4*)&ar[cc];
      acc += a4.x * l1w[(cc + 0) * 32 + h];
      acc += a4.y * l1w[(cc + 1) * 32 + h];
      acc += a4.z * l1w[(cc + 2) * 32 + h];
      acc += a4.w * l1w[(cc + 3) * 32 + h];
    }
    float s2 = bn2g[h] * rsqrtf(bn2v[h] + EPSBN);
    float o2 = bn2b[h] - bn2m[h] * s2;
    h1_s[t][h] = fmaxf(acc * s2 + o2, 0.f);
  }
  __syncthreads();

  // stage 4: linear_w l2 (32->32)
  #pragma unroll
  for (int pp = 0; pp < 2; ++pp) {
    int P = tid + pp * 256;
    int t = P >> 5, h = P & 31;
    float acc = l2b[h];
    #pragma unroll
    for (int hh = 0; hh < 32; ++hh) acc += h1_s[t][hh] * l2w[hh * 32 + h];
    w_s[t][h] = acc;
  }
  __syncthreads();

  // stage 5: softmax over neighbors (t) per h
  if (tid < H_W) {
    int h = tid;
    float m = -1e30f;
    #pragma unroll
    for (int t = 0; t < NSAMP; ++t) m = fmaxf(m, w_s[t][h]);
    float e[NSAMP];
    float ssum = 0.f;
    #pragma unroll
    for (int t = 0; t < NSAMP; ++t) { e[t] = __expf(w_s[t][h] - m); ssum += e[t]; }
    float inv = 1.f / ssum;
    #pragma unroll
    for (int t = 0; t < NSAMP; ++t) w_s[t][h] = e[t] * inv;
  }
  __syncthreads();

  // stage 6: weighted aggregation
  const int h = c & 31;
  float acc = 0.f;
  #pragma unroll
  for (int t = 0; t < NSAMP; ++t) {
    int j = jn[t];
    float xv = xqkv[(size_t)j * 768 + 512 + c];
    acc += (xv + pr_s[t][c]) * w_s[t][h];
  }
  out[(size_t)i * OUT_C + c] = acc;
}

// ---------------------------------------------------------------- launch
extern "C" void kernel_launch(void* const* d_in, const int* in_sizes, int n_in,
                              void* d_out, int out_size, void* d_ws, size_t ws_size,
                              hipStream_t stream) {
  const float* p    = (const float*)d_in[0];
  const float* x    = (const float*)d_in[1];
  const float* wq   = (const float*)d_in[2];
  const float* bq   = (const float*)d_in[3];
  const float* wk   = (const float*)d_in[4];
  const float* bk   = (const float*)d_in[5];
  const float* wv   = (const float*)d_in[6];
  const float* bv   = (const float*)d_in[7];
  const float* pw1  = (const float*)d_in[8];
  const float* pb1  = (const float*)d_in[9];
  const float* pbng = (const float*)d_in[10];
  const float* pbnb = (const float*)d_in[11];
  const float* pbnm = (const float*)d_in[12];
  const float* pbnv = (const float*)d_in[13];
  const float* pw2  = (const float*)d_in[14];
  const float* pb2  = (const float*)d_in[15];
  const float* bn1g = (const float*)d_in[16];
  const float* bn1b = (const float*)d_in[17];
  const float* bn1m = (const float*)d_in[18];
  const float* bn1v = (const float*)d_in[19];
  const float* l1w  = (const float*)d_in[20];
  const float* l1b  = (const float*)d_in[21];
  const float* bn2g = (const float*)d_in[22];
  const float* bn2b = (const float*)d_in[23];
  const float* bn2m = (const float*)d_in[24];
  const float* bn2v = (const float*)d_in[25];
  const float* l2w  = (const float*)d_in[26];
  const float* l2b  = (const float*)d_in[27];
  float* out = (float*)d_out;

  char* ws = (char*)d_ws;
  float4* p4   = (float4*)(ws + 0);                          // 128 KB
  float* Wp    = (float*)(ws + (1ull << 20));                // 768 KB
  float* biasp = (float*)(ws + (2ull << 20));                // 3 KB
  float* xqkv  = (float*)(ws + (3ull << 20));                // 24 MB
  unsigned long long* partial = (unsigned long long*)(ws + (28ull << 20)); // 16 MB
  int* nbr     = (int*)(ws + (45ull << 20));                 // 512 KB

  prep_kernel<<<dim3(768), dim3(256), 0, stream>>>(p, wq, wk, wv, bq, bk, bv, p4, Wp, biasp);
  gemm_qkv<<<dim3((N_PTS / 64) * (768 / 64)), dim3(256), 0, stream>>>(x, Wp, biasp, xqkv);
  knn_partial<<<dim3((N_PTS / 256) * KNN_SPLIT), dim3(256), 0, stream>>>(p4, partial);
  knn_merge<<<dim3(N_PTS / 256), dim3(256), 0, stream>>>(partial, nbr);
  fused_pt<<<dim3(N_PTS), dim3(256), 0, stream>>>(
      p, xqkv, nbr, pw1, pb1, pbng, pbnb, pbnm, pbnv, pw2, pb2,
      bn1g, bn1b, bn1m, bn1v, l1w, l1b, bn2g, bn2b, bn2m, bn2v, l2w, l2b, out);
}

// Round 3
// 551.932 us; speedup vs baseline: 1.7158x; 1.7158x over previous
//
#include <hip/hip_runtime.h>
#include <hip/hip_bf16.h>
#include <math.h>

#define N_PTS 8192
#define C_IN  256
#define OUT_C 256
#define NSAMP 16
#define H_W   32
#define EPSBN 1e-5f

#define SPLIT1 32
#define CHUNK1 256
#define SPLIT2 16
#define CHUNK2 512
#define CAP    64

// EXACT round-1 arithmetic (passed on this dataset): plain expression, default
// compiler contraction, shared by both passes. Do NOT change the rounding.
__device__ __forceinline__ float dist2(const float4 a, const float4 b) {
  float dot = a.x * b.x + a.y * b.y + a.z * b.z;
  return a.w + b.w - 2.0f * dot;
}

// ---------------------------------------------------------------- prep
__global__ __launch_bounds__(256) void prep_kernel(
    const float* __restrict__ p,
    const float* __restrict__ wq, const float* __restrict__ wk, const float* __restrict__ wv,
    const float* __restrict__ bq, const float* __restrict__ bk, const float* __restrict__ bv,
    float4* __restrict__ p4, float* __restrict__ Wp, float* __restrict__ biasp,
    int* __restrict__ cnt) {
  int tid = blockIdx.x * blockDim.x + threadIdx.x;
  int total = 256 * 768;
  if (tid < total) {
    int k = tid / 768, m = tid % 768;
    float v;
    if (m < 256)      v = wq[k * 256 + m];
    else if (m < 512) v = wk[k * 256 + (m - 256)];
    else              v = wv[k * 256 + (m - 512)];
    Wp[tid] = v;
  }
  if (tid < 768) {
    biasp[tid] = tid < 256 ? bq[tid] : (tid < 512 ? bk[tid - 256] : bv[tid - 512]);
  }
  if (tid < N_PTS) {
    float x = p[tid * 3 + 0], y = p[tid * 3 + 1], z = p[tid * 3 + 2];
    float sq = x * x;
    sq += y * y;
    sq += z * z;
    p4[tid] = make_float4(x, y, z, sq);
    cnt[tid] = 0;
  }
}

// ---------------------------------------------------------------- qkv gemm (fp32, 64x64x16 tiles)
__global__ __launch_bounds__(256) void gemm_qkv(
    const float* __restrict__ x, const float* __restrict__ Wp,
    const float* __restrict__ biasp, float* __restrict__ xqkv) {
  __shared__ float As[16][64];  // [k][m]
  __shared__ float Bs[16][64];  // [k][n]
  const int bm = blockIdx.x % (N_PTS / 64);
  const int bn = blockIdx.x / (N_PTS / 64);
  const int tid = threadIdx.x;
  const int tm = tid % 16, tn = tid / 16;
  const int ar = tid / 4, ac = tid % 4;   // A-load: row, col-quad
  const int br = tid / 16, bc = tid % 16; // B-load: row, col-quad

  float acc[4][4];
  #pragma unroll
  for (int i = 0; i < 4; ++i)
    #pragma unroll
    for (int j = 0; j < 4; ++j) acc[i][j] = 0.f;

  for (int k0 = 0; k0 < C_IN; k0 += 16) {
    float4 av = *(const float4*)&x[(size_t)(bm * 64 + ar) * C_IN + k0 + ac * 4];
    float4 bv = *(const float4*)&Wp[(size_t)(k0 + br) * 768 + bn * 64 + bc * 4];
    __syncthreads();
    As[ac * 4 + 0][ar] = av.x;
    As[ac * 4 + 1][ar] = av.y;
    As[ac * 4 + 2][ar] = av.z;
    As[ac * 4 + 3][ar] = av.w;
    *(float4*)&Bs[br][bc * 4] = bv;
    __syncthreads();
    #pragma unroll
    for (int kk = 0; kk < 16; ++kk) {
      float a0 = As[kk][tm * 4 + 0], a1 = As[kk][tm * 4 + 1];
      float a2 = As[kk][tm * 4 + 2], a3 = As[kk][tm * 4 + 3];
      float b0 = Bs[kk][tn * 4 + 0], b1 = Bs[kk][tn * 4 + 1];
      float b2 = Bs[kk][tn * 4 + 2], b3 = Bs[kk][tn * 4 + 3];
      acc[0][0] += a0 * b0; acc[0][1] += a0 * b1; acc[0][2] += a0 * b2; acc[0][3] += a0 * b3;
      acc[1][0] += a1 * b0; acc[1][1] += a1 * b1; acc[1][2] += a1 * b2; acc[1][3] += a1 * b3;
      acc[2][0] += a2 * b0; acc[2][1] += a2 * b1; acc[2][2] += a2 * b2; acc[2][3] += a2 * b3;
      acc[3][0] += a3 * b0; acc[3][1] += a3 * b1; acc[3][2] += a3 * b2; acc[3][3] += a3 * b3;
    }
  }
  const int col = bn * 64 + tn * 4;
  float4 b4 = *(const float4*)&biasp[col];
  #pragma unroll
  for (int i = 0; i < 4; ++i) {
    int row = bm * 64 + tm * 4 + i;
    float4 o;
    o.x = acc[i][0] + b4.x; o.y = acc[i][1] + b4.y;
    o.z = acc[i][2] + b4.z; o.w = acc[i][3] + b4.w;
    *(float4*)&xqkv[(size_t)row * 768 + col] = o;
  }
}

// ---------------------------------------------------------------- knn pass 1: f32 value-only top-16 per chunk
__global__ __launch_bounds__(256) void knn_thr(
    const float4* __restrict__ p4, float* __restrict__ partial) {
  __shared__ float4 cs[CHUNK1];
  const int pt = (blockIdx.x % (N_PTS / 256)) * 256 + threadIdx.x;
  const int chunk = blockIdx.x / (N_PTS / 256);
  const int j0 = chunk * CHUNK1;
  cs[threadIdx.x] = p4[j0 + threadIdx.x];
  __syncthreads();
  const float4 pi = p4[pt];
  float a[16];  // sorted DESCENDING: a[0] = 16th-best (largest kept)
  #pragma unroll
  for (int s = 0; s < 16; ++s) a[s] = 3.0e38f;
  for (int jj = 0; jj < CHUNK1; ++jj) {
    float d = dist2(pi, cs[jj]);
    if (d < a[0]) {
      #pragma unroll
      for (int s = 0; s < 15; ++s) a[s] = fmaxf(a[s + 1], fminf(a[s], d));
      a[15] = fminf(a[15], d);
    }
  }
  float* dst = &partial[((size_t)pt * SPLIT1 + chunk) * 16];
  #pragma unroll
  for (int s = 0; s < 16; ++s) dst[s] = a[15 - s];  // store ASCENDING
}

// ---------------------------------------------------------------- knn merge: bitonic top-16 of 32 sorted lists -> thr
__global__ __launch_bounds__(256) void knn_merge_thr(
    const float* __restrict__ partial, float* __restrict__ thr) {
  const int pt = blockIdx.x * 256 + threadIdx.x;
  const float* src = &partial[(size_t)pt * SPLIT1 * 16];
  float A[16];
  #pragma unroll
  for (int s = 0; s < 16; ++s) A[s] = src[s];
  for (int c = 1; c < SPLIT1; ++c) {
    const float* b = src + c * 16;
    float t[16];
    #pragma unroll
    for (int i = 0; i < 16; ++i) t[i] = fminf(A[i], b[15 - i]);  // bitonic seq of 16 smallest
    #pragma unroll
    for (int k = 8; k >= 1; k >>= 1) {
      #pragma unroll
      for (int i = 0; i < 16; ++i) {
        if (!(i & k)) {
          float lo = fminf(t[i], t[i | k]);
          float hi = fmaxf(t[i], t[i | k]);
          t[i] = lo; t[i | k] = hi;
        }
      }
    }
    #pragma unroll
    for (int i = 0; i < 16; ++i) A[i] = t[i];
  }
  // exact 16th-smallest per pass-1 arithmetic + absolute margin so pass-2's
  // (possibly differently-contracted) d can never exclude a true top-16 entry
  thr[pt] = A[15] + 1e-5f;
}

// ---------------------------------------------------------------- knn pass 2: collect all j with d <= thr
__device__ __forceinline__ unsigned long long make_key(float d, int j) {
  unsigned int di = __float_as_uint(d);
  unsigned int ord = ((int)di >= 0) ? (di ^ 0x80000000u) : ~di;
  return ((unsigned long long)ord << 32) | (unsigned int)j;
}

__global__ __launch_bounds__(256) void knn_collect(
    const float4* __restrict__ p4, const float* __restrict__ thr,
    int* __restrict__ cnt, unsigned long long* __restrict__ buf) {
  __shared__ float4 cs[CHUNK2];
  const int pt = (blockIdx.x % (N_PTS / 256)) * 256 + threadIdx.x;
  const int chunk = blockIdx.x / (N_PTS / 256);
  const int j0 = chunk * CHUNK2;
  cs[threadIdx.x] = p4[j0 + threadIdx.x];
  cs[threadIdx.x + 256] = p4[j0 + 256 + threadIdx.x];
  __syncthreads();
  const float4 pi = p4[pt];
  const float t = thr[pt];
  for (int jj = 0; jj < CHUNK2; ++jj) {
    float d = dist2(pi, cs[jj]);
    if (d <= t) {
      int pos = atomicAdd(&cnt[pt], 1);
      if (pos < CAP) buf[(size_t)pt * CAP + pos] = make_key(d, j0 + jj);
    }
  }
}

// ---------------------------------------------------------------- knn select: exact top-16 by (dist, idx) key
__device__ __forceinline__ void chain_insert(unsigned long long (&ak)[16], unsigned long long key) {
  if (key < ak[0]) {
    #pragma unroll
    for (int s = 0; s < 15; ++s) {
      unsigned long long mn = ak[s] < key ? ak[s] : key;
      unsigned long long nx = ak[s + 1];
      ak[s] = nx > mn ? nx : mn;
    }
    ak[15] = ak[15] < key ? ak[15] : key;
  }
}

__global__ __launch_bounds__(256) void knn_select(
    const int* __restrict__ cnt, const unsigned long long* __restrict__ buf,
    int* __restrict__ nbr) {
  const int pt = blockIdx.x * 256 + threadIdx.x;
  int n = cnt[pt];
  if (n > CAP) n = CAP;
  unsigned long long ak[16];
  #pragma unroll
  for (int s = 0; s < 16; ++s) ak[s] = ~0ULL;
  const unsigned long long* src = &buf[(size_t)pt * CAP];
  for (int e = 0; e < n; ++e) chain_insert(ak, src[e]);
  #pragma unroll
  for (int s = 0; s < 16; ++s) nbr[pt * NSAMP + s] = (int)(ak[s] & 0xFFFFFFFFu);
}

// ---------------------------------------------------------------- fused per-point transform
__global__ __launch_bounds__(256) void fused_pt(
    const float* __restrict__ p, const float* __restrict__ xqkv, const int* __restrict__ nbr,
    const float* __restrict__ pw1, const float* __restrict__ pb1,
    const float* __restrict__ pbng, const float* __restrict__ pbnb,
    const float* __restrict__ pbnm, const float* __restrict__ pbnv,
    const float* __restrict__ pw2, const float* __restrict__ pb2,
    const float* __restrict__ bn1g, const float* __restrict__ bn1b,
    const float* __restrict__ bn1m, const float* __restrict__ bn1v,
    const float* __restrict__ l1w, const float* __restrict__ l1b,
    const float* __restrict__ bn2g, const float* __restrict__ bn2b,
    const float* __restrict__ bn2m, const float* __restrict__ bn2v,
    const float* __restrict__ l2w, const float* __restrict__ l2b,
    float* __restrict__ out) {
  __shared__ float pr_s[NSAMP][OUT_C];   // 16 KB
  __shared__ float a_s[NSAMP][C_IN];     // 16 KB
  __shared__ float h1_s[NSAMP][H_W];     // 2 KB
  __shared__ float w_s[NSAMP][H_W];      // 2 KB
  __shared__ float q3_s[NSAMP][4];
  __shared__ int jn[NSAMP];

  const int i = blockIdx.x;
  const int tid = threadIdx.x;

  if (tid < NSAMP) {
    int j = nbr[i * NSAMP + tid];
    jn[tid] = j;
    float rx = p[j * 3 + 0] - p[i * 3 + 0];
    float ry = p[j * 3 + 1] - p[i * 3 + 1];
    float rz = p[j * 3 + 2] - p[i * 3 + 2];
    #pragma unroll
    for (int c3 = 0; c3 < 3; ++c3) {
      float t = rx * pw1[0 * 3 + c3] + ry * pw1[1 * 3 + c3] + rz * pw1[2 * 3 + c3] + pb1[c3];
      t = (t - pbnm[c3]) * rsqrtf(pbnv[c3] + EPSBN) * pbng[c3] + pbnb[c3];
      q3_s[tid][c3] = fmaxf(t, 0.f);
    }
  }
  __syncthreads();

  const int c = tid;
  const float xq_c = xqkv[(size_t)i * 768 + c];
  const float s1 = bn1g[c] * rsqrtf(bn1v[c] + EPSBN);
  const float o1 = bn1b[c] - bn1m[c] * s1;
  const float w2c0 = pw2[0 * 256 + c], w2c1 = pw2[256 + c], w2c2 = pw2[512 + c];
  const float pb2c = pb2[c];
  #pragma unroll
  for (int t = 0; t < NSAMP; ++t) {
    int j = jn[t];
    float prv = q3_s[t][0] * w2c0 + q3_s[t][1] * w2c1 + q3_s[t][2] * w2c2 + pb2c;
    pr_s[t][c] = prv;
    float xkv = xqkv[(size_t)j * 768 + 256 + c];
    float r = xkv - xq_c + prv;
    a_s[t][c] = fmaxf(r * s1 + o1, 0.f);
  }
  __syncthreads();

  #pragma unroll
  for (int pp = 0; pp < 2; ++pp) {
    int P = tid + pp * 256;
    int t = P >> 5, h = P & 31;
    float acc = l1b[h];
    const float* ar = a_s[t];
    #pragma unroll 4
    for (int cc = 0; cc < 256; cc += 4) {
      float4 a4 = *(const float4*)&ar[cc];
      acc += a4.x * l1w[(cc + 0) * 32 + h];
      acc += a4.y * l1w[(cc + 1) * 32 + h];
      acc += a4.z * l1w[(cc + 2) * 32 + h];
      acc += a4.w * l1w[(cc + 3) * 32 + h];
    }
    float s2 = bn2g[h] * rsqrtf(bn2v[h] + EPSBN);
    float o2 = bn2b[h] - bn2m[h] * s2;
    h1_s[t][h] = fmaxf(acc * s2 + o2, 0.f);
  }
  __syncthreads();

  #pragma unroll
  for (int pp = 0; pp < 2; ++pp) {
    int P = tid + pp * 256;
    int t = P >> 5, h = P & 31;
    float acc = l2b[h];
    #pragma unroll
    for (int hh = 0; hh < 32; ++hh) acc += h1_s[t][hh] * l2w[hh * 32 + h];
    w_s[t][h] = acc;
  }
  __syncthreads();

  if (tid < H_W) {
    int h = tid;
    float m = -1e30f;
    #pragma unroll
    for (int t = 0; t < NSAMP; ++t) m = fmaxf(m, w_s[t][h]);
    float e[NSAMP];
    float ssum = 0.f;
    #pragma unroll
    for (int t = 0; t < NSAMP; ++t) { e[t] = __expf(w_s[t][h] - m); ssum += e[t]; }
    float inv = 1.f / ssum;
    #pragma unroll
    for (int t = 0; t < NSAMP; ++t) w_s[t][h] = e[t] * inv;
  }
  __syncthreads();

  const int h = c & 31;
  float acc = 0.f;
  #pragma unroll
  for (int t = 0; t < NSAMP; ++t) {
    int j = jn[t];
    float xv = xqkv[(size_t)j * 768 + 512 + c];
    acc += (xv + pr_s[t][c]) * w_s[t][h];
  }
  out[(size_t)i * OUT_C + c] = acc;
}

// ---------------------------------------------------------------- launch
extern "C" void kernel_launch(void* const* d_in, const int* in_sizes, int n_in,
                              void* d_out, int out_size, void* d_ws, size_t ws_size,
                              hipStream_t stream) {
  const float* p    = (const float*)d_in[0];
  const float* x    = (const float*)d_in[1];
  const float* wq   = (const float*)d_in[2];
  const float* bq   = (const float*)d_in[3];
  const float* wk   = (const float*)d_in[4];
  const float* bk   = (const float*)d_in[5];
  const float* wv   = (const float*)d_in[6];
  const float* bv   = (const float*)d_in[7];
  const float* pw1  = (const float*)d_in[8];
  const float* pb1  = (const float*)d_in[9];
  const float* pbng = (const float*)d_in[10];
  const float* pbnb = (const float*)d_in[11];
  const float* pbnm = (const float*)d_in[12];
  const float* pbnv = (const float*)d_in[13];
  const float* pw2  = (const float*)d_in[14];
  const float* pb2  = (const float*)d_in[15];
  const float* bn1g = (const float*)d_in[16];
  const float* bn1b = (const float*)d_in[17];
  const float* bn1m = (const float*)d_in[18];
  const float* bn1v = (const float*)d_in[19];
  const float* l1w  = (const float*)d_in[20];
  const float* l1b  = (const float*)d_in[21];
  const float* bn2g = (const float*)d_in[22];
  const float* bn2b = (const float*)d_in[23];
  const float* bn2m = (const float*)d_in[24];
  const float* bn2v = (const float*)d_in[25];
  const float* l2w  = (const float*)d_in[26];
  const float* l2b  = (const float*)d_in[27];
  float* out = (float*)d_out;

  char* ws = (char*)d_ws;
  float4* p4   = (float4*)(ws + 0);                 // 128 KB
  float* Wp    = (float*)(ws + 0x40000);            // 768 KB
  float* biasp = (float*)(ws + 0x100000);           // 3 KB
  int*   cnt   = (int*)(ws + 0x110000);             // 32 KB
  float* thr   = (float*)(ws + 0x120000);           // 32 KB
  int*   nbr   = (int*)(ws + 0x140000);             // 512 KB
  unsigned long long* buf = (unsigned long long*)(ws + 0x200000);  // 4 MB
  float* partial = (float*)(ws + (6ull << 20));     // 16 MB
  float* xqkv  = (float*)(ws + (22ull << 20));      // 24 MB (ends at 46 MB)

  prep_kernel<<<dim3(768), dim3(256), 0, stream>>>(p, wq, wk, wv, bq, bk, bv, p4, Wp, biasp, cnt);
  gemm_qkv<<<dim3((N_PTS / 64) * (768 / 64)), dim3(256), 0, stream>>>(x, Wp, biasp, xqkv);
  knn_thr<<<dim3((N_PTS / 256) * SPLIT1), dim3(256), 0, stream>>>(p4, partial);
  knn_merge_thr<<<dim3(N_PTS / 256), dim3(256), 0, stream>>>(partial, thr);
  knn_collect<<<dim3((N_PTS / 256) * SPLIT2), dim3(256), 0, stream>>>(p4, thr, cnt, buf);
  knn_select<<<dim3(N_PTS / 256), dim3(256), 0, stream>>>(cnt, buf, nbr);
  fused_pt<<<dim3(N_PTS), dim3(256), 0, stream>>>(
      p, xqkv, nbr, pw1, pb1, pbng, pbnb, pbnm, pbnv, pw2, pb2,
      bn1g, bn1b, bn1m, bn1v, l1w, l1b, bn2g, bn2b, bn2m, bn2v, l2w, l2b, out);
}

// Round 4
// 398.188 us; speedup vs baseline: 2.3783x; 1.3861x over previous
//
#include <hip/hip_runtime.h>
#include <hip/hip_bf16.h>
#include <math.h>

#define N_PTS 8192
#define C_IN  256
#define OUT_C 256
#define NSAMP 16
#define H_W   32
#define EPSBN 1e-5f

#define SPLIT1 32
#define CHUNK1 256
#define SPLIT2 16
#define CHUNK2 512
#define CAP    64

typedef short bf16x8 __attribute__((ext_vector_type(8)));
typedef float f32x4  __attribute__((ext_vector_type(4)));

// EXACT round-1 arithmetic (passed on this dataset): plain expression, default
// compiler contraction, shared by both passes. Do NOT change the rounding.
__device__ __forceinline__ float dist2(const float4 a, const float4 b) {
  float dot = a.x * b.x + a.y * b.y + a.z * b.z;
  return a.w + b.w - 2.0f * dot;
}

// ---------------------------------------------------------------- prep
// Packs: p4 (+|p|^2), bf16 x, bf16 QKV weights in MFMA B-fragment layout,
// bf16 l1w/l2w in B-fragment layout, fp32 fused bias, zeroed cnt.
__global__ __launch_bounds__(256) void prep_kernel(
    const float* __restrict__ p, const float* __restrict__ x,
    const float* __restrict__ wq, const float* __restrict__ wk, const float* __restrict__ wv,
    const float* __restrict__ bq, const float* __restrict__ bk, const float* __restrict__ bv,
    const float* __restrict__ l1w, const float* __restrict__ l2w,
    float4* __restrict__ p4, __hip_bfloat16* __restrict__ Bp, float* __restrict__ biasp,
    int* __restrict__ cnt, __hip_bfloat16* __restrict__ x_bf,
    __hip_bfloat16* __restrict__ l1wp, __hip_bfloat16* __restrict__ l2wp) {
  int tid = blockIdx.x * blockDim.x + threadIdx.x;
  // B-fragment pack of [256 x 768] qkv weight: flat = ((nt*32+kb)*16+n)*8+kj
  if (tid < 48 * 32 * 16 * 8) {
    int kj = tid & 7, n = (tid >> 3) & 15, kb = (tid >> 7) & 31, nt = tid >> 12;
    int k = kb * 8 + kj, col = nt * 16 + n;
    float v;
    if (col < 256)      v = wq[k * 256 + col];
    else if (col < 512) v = wk[k * 256 + (col - 256)];
    else                v = wv[k * 256 + (col - 512)];
    Bp[tid] = __float2bfloat16(v);
  }
  if (tid < 768) {
    biasp[tid] = tid < 256 ? bq[tid] : (tid < 512 ? bk[tid - 256] : bv[tid - 512]);
  }
  if (tid < 8192) {
    // l1w [256 x 32] fragment pack
    int kj = tid & 7, n = (tid >> 3) & 15, kb = (tid >> 7) & 31, nt = (tid >> 12) & 1;
    int k = kb * 8 + kj, col = nt * 16 + n;
    l1wp[tid] = __float2bfloat16(l1w[k * 32 + col]);
  }
  if (tid < 1024) {
    // l2w [32 x 32] fragment pack
    int kj = tid & 7, n = (tid >> 3) & 15, kb = (tid >> 7) & 3, nt = (tid >> 9) & 1;
    int k = kb * 8 + kj, col = nt * 16 + n;
    l2wp[tid] = __float2bfloat16(l2w[k * 32 + col]);
  }
  if (tid < N_PTS) {
    float px = p[tid * 3 + 0], py = p[tid * 3 + 1], pz = p[tid * 3 + 2];
    float sq = px * px;
    sq += py * py;
    sq += pz * pz;
    p4[tid] = make_float4(px, py, pz, sq);
    cnt[tid] = 0;
  }
  if (tid < N_PTS * C_IN) x_bf[tid] = __float2bfloat16(x[tid]);
}

// ---------------------------------------------------------------- qkv gemm: bf16 MFMA, no LDS
// One wave per 64x64 output tile; A/B fragments loaded directly (L2-resident).
__global__ __launch_bounds__(256) void gemm_qkv_mfma(
    const __hip_bfloat16* __restrict__ x_bf, const __hip_bfloat16* __restrict__ Bp,
    const float* __restrict__ biasp, __hip_bfloat16* __restrict__ xqkv) {
  const int w = threadIdx.x >> 6;
  const int lane = threadIdx.x & 63;
  const int gw = blockIdx.x * 4 + w;          // 1536 waves: 128 m-tiles x 12 n-tiles
  const int m0 = (gw & 127) * 64;
  const int nt4 = (gw >> 7) * 4;              // base n-tile (16-col units)
  const int n = lane & 15, q = lane >> 4;

  f32x4 acc[4][4];
  #pragma unroll
  for (int mi = 0; mi < 4; ++mi)
    #pragma unroll
    for (int ni = 0; ni < 4; ++ni) acc[mi][ni] = (f32x4){0.f, 0.f, 0.f, 0.f};

  for (int k0 = 0; k0 < 256; k0 += 32) {
    bf16x8 af[4], bfr[4];
    #pragma unroll
    for (int mi = 0; mi < 4; ++mi)
      af[mi] = *(const bf16x8*)&x_bf[(size_t)(m0 + mi * 16 + n) * 256 + k0 + q * 8];
    #pragma unroll
    for (int ni = 0; ni < 4; ++ni)
      bfr[ni] = *(const bf16x8*)&Bp[(size_t)(nt4 + ni) * 4096 + (k0 >> 3) * 128 + q * 128 + n * 8];
    #pragma unroll
    for (int mi = 0; mi < 4; ++mi)
      #pragma unroll
      for (int ni = 0; ni < 4; ++ni)
        acc[mi][ni] = __builtin_amdgcn_mfma_f32_16x16x32_bf16(af[mi], bfr[ni], acc[mi][ni], 0, 0, 0);
  }
  #pragma unroll
  for (int ni = 0; ni < 4; ++ni) {
    int col = (nt4 + ni) * 16 + n;
    float b = biasp[col];
    #pragma unroll
    for (int mi = 0; mi < 4; ++mi)
      #pragma unroll
      for (int r = 0; r < 4; ++r)
        xqkv[(size_t)(m0 + mi * 16 + q * 4 + r) * 768 + col] = __float2bfloat16(acc[mi][ni][r] + b);
  }
}

// ---------------------------------------------------------------- knn pass 1: f32 value-only top-16 per chunk
__global__ __launch_bounds__(256) void knn_thr(
    const float4* __restrict__ p4, float* __restrict__ partial) {
  __shared__ float4 cs[CHUNK1];
  const int pt = (blockIdx.x % (N_PTS / 256)) * 256 + threadIdx.x;
  const int chunk = blockIdx.x / (N_PTS / 256);
  const int j0 = chunk * CHUNK1;
  cs[threadIdx.x] = p4[j0 + threadIdx.x];
  __syncthreads();
  const float4 pi = p4[pt];
  float a[16];  // sorted DESCENDING: a[0] = 16th-best (largest kept)
  #pragma unroll
  for (int s = 0; s < 16; ++s) a[s] = 3.0e38f;
  for (int jj = 0; jj < CHUNK1; ++jj) {
    float d = dist2(pi, cs[jj]);
    if (d < a[0]) {
      #pragma unroll
      for (int s = 0; s < 15; ++s) a[s] = fmaxf(a[s + 1], fminf(a[s], d));
      a[15] = fminf(a[15], d);
    }
  }
  float* dst = &partial[((size_t)pt * SPLIT1 + chunk) * 16];
  #pragma unroll
  for (int s = 0; s < 16; ++s) dst[s] = a[15 - s];  // store ASCENDING
}

// ---------------------------------------------------------------- knn merge: bitonic top-16 of 32 sorted lists -> thr
__global__ __launch_bounds__(256) void knn_merge_thr(
    const float* __restrict__ partial, float* __restrict__ thr) {
  const int pt = blockIdx.x * 256 + threadIdx.x;
  const float* src = &partial[(size_t)pt * SPLIT1 * 16];
  float A[16];
  #pragma unroll
  for (int s = 0; s < 16; ++s) A[s] = src[s];
  for (int c = 1; c < SPLIT1; ++c) {
    const float* b = src + c * 16;
    float t[16];
    #pragma unroll
    for (int i = 0; i < 16; ++i) t[i] = fminf(A[i], b[15 - i]);
    #pragma unroll
    for (int k = 8; k >= 1; k >>= 1) {
      #pragma unroll
      for (int i = 0; i < 16; ++i) {
        if (!(i & k)) {
          float lo = fminf(t[i], t[i | k]);
          float hi = fmaxf(t[i], t[i | k]);
          t[i] = lo; t[i | k] = hi;
        }
      }
    }
    #pragma unroll
    for (int i = 0; i < 16; ++i) A[i] = t[i];
  }
  thr[pt] = A[15] + 1e-5f;  // margin vs cross-kernel contraction differences
}

// ---------------------------------------------------------------- knn pass 2: collect all j with d <= thr
__device__ __forceinline__ unsigned long long make_key(float d, int j) {
  unsigned int di = __float_as_uint(d);
  unsigned int ord = ((int)di >= 0) ? (di ^ 0x80000000u) : ~di;
  return ((unsigned long long)ord << 32) | (unsigned int)j;
}

__global__ __launch_bounds__(256) void knn_collect(
    const float4* __restrict__ p4, const float* __restrict__ thr,
    int* __restrict__ cnt, unsigned long long* __restrict__ buf) {
  __shared__ float4 cs[CHUNK2];
  const int pt = (blockIdx.x % (N_PTS / 256)) * 256 + threadIdx.x;
  const int chunk = blockIdx.x / (N_PTS / 256);
  const int j0 = chunk * CHUNK2;
  cs[threadIdx.x] = p4[j0 + threadIdx.x];
  cs[threadIdx.x + 256] = p4[j0 + 256 + threadIdx.x];
  __syncthreads();
  const float4 pi = p4[pt];
  const float t = thr[pt];
  for (int jj = 0; jj < CHUNK2; ++jj) {
    float d = dist2(pi, cs[jj]);
    if (d <= t) {
      int pos = atomicAdd(&cnt[pt], 1);
      if (pos < CAP) buf[(size_t)pt * CAP + pos] = make_key(d, j0 + jj);
    }
  }
}

// ---------------------------------------------------------------- knn select: exact top-16 by (dist, idx) key
__device__ __forceinline__ void chain_insert(unsigned long long (&ak)[16], unsigned long long key) {
  if (key < ak[0]) {
    #pragma unroll
    for (int s = 0; s < 15; ++s) {
      unsigned long long mn = ak[s] < key ? ak[s] : key;
      unsigned long long nx = ak[s + 1];
      ak[s] = nx > mn ? nx : mn;
    }
    ak[15] = ak[15] < key ? ak[15] : key;
  }
}

__global__ __launch_bounds__(256) void knn_select(
    const int* __restrict__ cnt, const unsigned long long* __restrict__ buf,
    int* __restrict__ nbr) {
  const int pt = blockIdx.x * 256 + threadIdx.x;
  int n = cnt[pt];
  if (n > CAP) n = CAP;
  unsigned long long ak[16];
  #pragma unroll
  for (int s = 0; s < 16; ++s) ak[s] = ~0ULL;
  const unsigned long long* src = &buf[(size_t)pt * CAP];
  for (int e = 0; e < n; ++e) chain_insert(ak, src[e]);
  #pragma unroll
  for (int s = 0; s < 16; ++s) nbr[pt * NSAMP + s] = (int)(ak[s] & 0xFFFFFFFFu);
}

// ---------------------------------------------------------------- fused per-point transform (bf16 gather + MFMA linear_w)
__global__ __launch_bounds__(256) void fused_pt(
    const float* __restrict__ p, const __hip_bfloat16* __restrict__ xqkv,
    const int* __restrict__ nbr,
    const float* __restrict__ pw1, const float* __restrict__ pb1,
    const float* __restrict__ pbng, const float* __restrict__ pbnb,
    const float* __restrict__ pbnm, const float* __restrict__ pbnv,
    const float* __restrict__ pw2, const float* __restrict__ pb2,
    const float* __restrict__ bn1g, const float* __restrict__ bn1b,
    const float* __restrict__ bn1m, const float* __restrict__ bn1v,
    const __hip_bfloat16* __restrict__ l1wp, const float* __restrict__ l1b,
    const float* __restrict__ bn2g, const float* __restrict__ bn2b,
    const float* __restrict__ bn2m, const float* __restrict__ bn2v,
    const __hip_bfloat16* __restrict__ l2wp, const float* __restrict__ l2b,
    float* __restrict__ out) {
  __shared__ __align__(16) __hip_bfloat16 a_s[NSAMP][264];  // bn1(relu(r_qk)), +8 pad
  __shared__ __align__(16) __hip_bfloat16 h1_s[NSAMP][40];  // l1 activations, +8 pad
  __shared__ float w_s[NSAMP][33];
  __shared__ float q3_s[NSAMP][4];
  __shared__ int jn[NSAMP];

  const int i = blockIdx.x;
  const int tid = threadIdx.x;

  // stage 1: neighbor ids + linear_p first layer (3->3 + bn + relu)
  if (tid < NSAMP) {
    int j = nbr[i * NSAMP + tid];
    jn[tid] = j;
    float rx = p[j * 3 + 0] - p[i * 3 + 0];
    float ry = p[j * 3 + 1] - p[i * 3 + 1];
    float rz = p[j * 3 + 2] - p[i * 3 + 2];
    #pragma unroll
    for (int c3 = 0; c3 < 3; ++c3) {
      float t = rx * pw1[0 * 3 + c3] + ry * pw1[1 * 3 + c3] + rz * pw1[2 * 3 + c3] + pb1[c3];
      t = (t - pbnm[c3]) * rsqrtf(pbnv[c3] + EPSBN) * pbng[c3] + pbnb[c3];
      q3_s[tid][c3] = fmaxf(t, 0.f);
    }
  }
  __syncthreads();

  // stage 2: gather xk (bf16), r_qk, bn1+relu -> a_s (bf16)
  const int c = tid;
  const float xq_c = __bfloat162float(xqkv[(size_t)i * 768 + c]);
  const float s1 = bn1g[c] * rsqrtf(bn1v[c] + EPSBN);
  const float o1 = bn1b[c] - bn1m[c] * s1;
  const float w2c0 = pw2[c], w2c1 = pw2[256 + c], w2c2 = pw2[512 + c];
  const float pb2c = pb2[c];
  #pragma unroll
  for (int t = 0; t < NSAMP; ++t) {
    int j = jn[t];
    float prv = q3_s[t][0] * w2c0 + q3_s[t][1] * w2c1 + q3_s[t][2] * w2c2 + pb2c;
    float xkv = __bfloat162float(xqkv[(size_t)j * 768 + 256 + c]);
    float r = xkv - xq_c + prv;
    a_s[t][c] = __float2bfloat16(fmaxf(r * s1 + o1, 0.f));
  }
  __syncthreads();

  // stage 3: linear_w l1 (16x256 @ 256x32) via MFMA on waves 0,1 + bn2 + relu
  const int wv_ = tid >> 6;
  const int lane = tid & 63;
  const int nn = lane & 15, q = lane >> 4;
  if (wv_ < 2) {
    f32x4 acc = {0.f, 0.f, 0.f, 0.f};
    #pragma unroll
    for (int k0 = 0; k0 < 256; k0 += 32) {
      bf16x8 a = *(const bf16x8*)&a_s[nn][k0 + q * 8];
      bf16x8 b = *(const bf16x8*)&l1wp[wv_ * 4096 + (k0 >> 3) * 128 + q * 128 + nn * 8];
      acc = __builtin_amdgcn_mfma_f32_16x16x32_bf16(a, b, acc, 0, 0, 0);
    }
    int h = wv_ * 16 + nn;
    float s2 = bn2g[h] * rsqrtf(bn2v[h] + EPSBN);
    float o2 = bn2b[h] - bn2m[h] * s2;
    float l1bh = l1b[h];
    #pragma unroll
    for (int r = 0; r < 4; ++r)
      h1_s[q * 4 + r][h] = __float2bfloat16(fmaxf((acc[r] + l1bh) * s2 + o2, 0.f));
  }
  __syncthreads();

  // stage 4: linear_w l2 (16x32 @ 32x32) via single MFMA on waves 0,1
  if (wv_ < 2) {
    bf16x8 a = *(const bf16x8*)&h1_s[nn][q * 8];
    bf16x8 b = *(const bf16x8*)&l2wp[wv_ * 512 + q * 128 + nn * 8];
    f32x4 z = {0.f, 0.f, 0.f, 0.f};
    f32x4 d = __builtin_amdgcn_mfma_f32_16x16x32_bf16(a, b, z, 0, 0, 0);
    int h = wv_ * 16 + nn;
    float l2bh = l2b[h];
    #pragma unroll
    for (int r = 0; r < 4; ++r) w_s[q * 4 + r][h] = d[r] + l2bh;
  }
  __syncthreads();

  // stage 5: softmax over neighbors (t) per h
  if (tid < H_W) {
    int h = tid;
    float m = -1e30f;
    #pragma unroll
    for (int t = 0; t < NSAMP; ++t) m = fmaxf(m, w_s[t][h]);
    float e[NSAMP];
    float ssum = 0.f;
    #pragma unroll
    for (int t = 0; t < NSAMP; ++t) { e[t] = __expf(w_s[t][h] - m); ssum += e[t]; }
    float inv = 1.f / ssum;
    #pragma unroll
    for (int t = 0; t < NSAMP; ++t) w_s[t][h] = e[t] * inv;
  }
  __syncthreads();

  // stage 6: weighted aggregation (recompute pr; gather xv bf16)
  const int h = c & 31;
  float acc6 = 0.f;
  #pragma unroll
  for (int t = 0; t < NSAMP; ++t) {
    int j = jn[t];
    float xv = __bfloat162float(xqkv[(size_t)j * 768 + 512 + c]);
    float prv = q3_s[t][0] * w2c0 + q3_s[t][1] * w2c1 + q3_s[t][2] * w2c2 + pb2c;
    acc6 += (xv + prv) * w_s[t][h];
  }
  out[(size_t)i * OUT_C + c] = acc6;
}

// ---------------------------------------------------------------- launch
extern "C" void kernel_launch(void* const* d_in, const int* in_sizes, int n_in,
                              void* d_out, int out_size, void* d_ws, size_t ws_size,
                              hipStream_t stream) {
  const float* p    = (const float*)d_in[0];
  const float* x    = (const float*)d_in[1];
  const float* wq   = (const float*)d_in[2];
  const float* bq   = (const float*)d_in[3];
  const float* wk   = (const float*)d_in[4];
  const float* bk   = (const float*)d_in[5];
  const float* wv   = (const float*)d_in[6];
  const float* bv   = (const float*)d_in[7];
  const float* pw1  = (const float*)d_in[8];
  const float* pb1  = (const float*)d_in[9];
  const float* pbng = (const float*)d_in[10];
  const float* pbnb = (const float*)d_in[11];
  const float* pbnm = (const float*)d_in[12];
  const float* pbnv = (const float*)d_in[13];
  const float* pw2  = (const float*)d_in[14];
  const float* pb2  = (const float*)d_in[15];
  const float* bn1g = (const float*)d_in[16];
  const float* bn1b = (const float*)d_in[17];
  const float* bn1m = (const float*)d_in[18];
  const float* bn1v = (const float*)d_in[19];
  const float* l1w  = (const float*)d_in[20];
  const float* l1b  = (const float*)d_in[21];
  const float* bn2g = (const float*)d_in[22];
  const float* bn2b = (const float*)d_in[23];
  const float* bn2m = (const float*)d_in[24];
  const float* bn2v = (const float*)d_in[25];
  const float* l2w  = (const float*)d_in[26];
  const float* l2b  = (const float*)d_in[27];
  float* out = (float*)d_out;

  char* ws = (char*)d_ws;
  float4* p4   = (float4*)(ws + 0);                      // 128 KB
  float* biasp = (float*)(ws + 0x040000);                // 3 KB
  int*   cnt   = (int*)(ws + 0x060000);                  // 32 KB
  float* thr   = (float*)(ws + 0x080000);                // 32 KB
  __hip_bfloat16* l1wp = (__hip_bfloat16*)(ws + 0x0A0000);  // 16 KB
  __hip_bfloat16* l2wp = (__hip_bfloat16*)(ws + 0x0C0000);  // 2 KB
  int*   nbr   = (int*)(ws + 0x100000);                  // 512 KB
  unsigned long long* buf = (unsigned long long*)(ws + 0x200000);  // 4 MB
  __hip_bfloat16* Bp   = (__hip_bfloat16*)(ws + 0x600000);   // 384 KB
  __hip_bfloat16* x_bf = (__hip_bfloat16*)(ws + 0x700000);   // 4 MB
  __hip_bfloat16* xqkv = (__hip_bfloat16*)(ws + 0xB00000);   // 12 MB
  float* partial = (float*)(ws + 0x1800000);             // 16 MB (ends at 40 MB)

  prep_kernel<<<dim3(N_PTS), dim3(256), 0, stream>>>(
      p, x, wq, wk, wv, bq, bk, bv, l1w, l2w, p4, Bp, biasp, cnt, x_bf, l1wp, l2wp);
  gemm_qkv_mfma<<<dim3(384), dim3(256), 0, stream>>>(x_bf, Bp, biasp, xqkv);
  knn_thr<<<dim3((N_PTS / 256) * SPLIT1), dim3(256), 0, stream>>>(p4, partial);
  knn_merge_thr<<<dim3(N_PTS / 256), dim3(256), 0, stream>>>(partial, thr);
  knn_collect<<<dim3((N_PTS / 256) * SPLIT2), dim3(256), 0, stream>>>(p4, thr, cnt, buf);
  knn_select<<<dim3(N_PTS / 256), dim3(256), 0, stream>>>(cnt, buf, nbr);
  fused_pt<<<dim3(N_PTS), dim3(256), 0, stream>>>(
      p, xqkv, nbr, pw1, pb1, pbng, pbnb, pbnm, pbnv, pw2, pb2,
      bn1g, bn1b, bn1m, bn1v, l1wp, l1b, bn2g, bn2b, bn2m, bn2v, l2wp, l2b, out);
}

// Round 5
// 299.839 us; speedup vs baseline: 3.1584x; 1.3280x over previous
//
#include <hip/hip_runtime.h>
#include <hip/hip_bf16.h>
#include <math.h>

#define N_PTS 8192
#define C_IN  256
#define OUT_C 256
#define NSAMP 16
#define H_W   32
#define EPSBN 1e-5f
#define GDIM  8
#define NCELL (GDIM * GDIM * GDIM)

typedef short bf16x8 __attribute__((ext_vector_type(8)));
typedef float f32x4  __attribute__((ext_vector_type(4)));

// EXACT arithmetic from the passing rounds: plain expression, default
// compiler contraction, shared by all scans. Do NOT change the rounding.
__device__ __forceinline__ float dist2(const float4 a, const float4 b) {
  float dot = a.x * b.x + a.y * b.y + a.z * b.z;
  return a.w + b.w - 2.0f * dot;
}

__device__ __forceinline__ unsigned long long make_key(float d, int j) {
  unsigned int di = __float_as_uint(d);
  unsigned int ord = ((int)di >= 0) ? (di ^ 0x80000000u) : ~di;
  return ((unsigned long long)ord << 32) | (unsigned int)j;
}

__device__ __forceinline__ void chain_insert(unsigned long long (&ak)[16], unsigned long long key) {
  if (key < ak[0]) {
    #pragma unroll
    for (int s = 0; s < 15; ++s) {
      unsigned long long mn = ak[s] < key ? ak[s] : key;
      unsigned long long nx = ak[s + 1];
      ak[s] = nx > mn ? nx : mn;
    }
    ak[15] = ak[15] < key ? ak[15] : key;
  }
}

// ---------------------------------------------------------------- prep
// p4 (+|p|^2), bf16 x, fragment-packed bf16 weights, fused bias, grid histogram.
__global__ __launch_bounds__(256) void prep_kernel(
    const float* __restrict__ p, const float* __restrict__ x,
    const float* __restrict__ wq, const float* __restrict__ wk, const float* __restrict__ wv,
    const float* __restrict__ bq, const float* __restrict__ bk, const float* __restrict__ bv,
    const float* __restrict__ l1w, const float* __restrict__ l2w,
    float4* __restrict__ p4, __hip_bfloat16* __restrict__ Bp, float* __restrict__ biasp,
    __hip_bfloat16* __restrict__ x_bf,
    __hip_bfloat16* __restrict__ l1wp, __hip_bfloat16* __restrict__ l2wp,
    int* __restrict__ hist, int* __restrict__ pt_cell) {
  int tid = blockIdx.x * blockDim.x + threadIdx.x;
  // B-fragment pack of [256 x 768] qkv weight: flat = ((nt*32+kb)*16+n)*8+kj
  if (tid < 48 * 32 * 16 * 8) {
    int kj = tid & 7, n = (tid >> 3) & 15, kb = (tid >> 7) & 31, nt = tid >> 12;
    int k = kb * 8 + kj, col = nt * 16 + n;
    float v;
    if (col < 256)      v = wq[k * 256 + col];
    else if (col < 512) v = wk[k * 256 + (col - 256)];
    else                v = wv[k * 256 + (col - 512)];
    Bp[tid] = __float2bfloat16(v);
  }
  if (tid < 768) {
    biasp[tid] = tid < 256 ? bq[tid] : (tid < 512 ? bk[tid - 256] : bv[tid - 512]);
  }
  if (tid < 8192) {
    int kj = tid & 7, n = (tid >> 3) & 15, kb = (tid >> 7) & 31, nt = (tid >> 12) & 1;
    int k = kb * 8 + kj, col = nt * 16 + n;
    l1wp[tid] = __float2bfloat16(l1w[k * 32 + col]);
  }
  if (tid < 1024) {
    int kj = tid & 7, n = (tid >> 3) & 15, kb = (tid >> 7) & 3, nt = (tid >> 9) & 1;
    int k = kb * 8 + kj, col = nt * 16 + n;
    l2wp[tid] = __float2bfloat16(l2w[k * 32 + col]);
  }
  if (tid < N_PTS) {
    float px = p[tid * 3 + 0], py = p[tid * 3 + 1], pz = p[tid * 3 + 2];
    float sq = px * px;
    sq += py * py;
    sq += pz * pz;
    p4[tid] = make_float4(px, py, pz, sq);
    int cx = min(GDIM - 1, max(0, (int)(px * GDIM)));
    int cy = min(GDIM - 1, max(0, (int)(py * GDIM)));
    int cz = min(GDIM - 1, max(0, (int)(pz * GDIM)));
    int cell = (cz * GDIM + cy) * GDIM + cx;
    pt_cell[tid] = cell;
    atomicAdd(&hist[cell], 1);   // hist zeroed by hipMemsetAsync before this kernel
  }
  if (tid < N_PTS * C_IN) x_bf[tid] = __float2bfloat16(x[tid]);
}

// ---------------------------------------------------------------- grid scan (exclusive prefix over 512 cells)
__global__ __launch_bounds__(512) void scan512(const int* __restrict__ hist, int* __restrict__ cell_start) {
  __shared__ int buf[NCELL];
  int t = threadIdx.x;
  buf[t] = hist[t];
  __syncthreads();
  for (int off = 1; off < NCELL; off <<= 1) {
    int add = (t >= off) ? buf[t - off] : 0;
    __syncthreads();
    buf[t] += add;
    __syncthreads();
  }
  cell_start[t + 1] = buf[t];
  if (t == 0) cell_start[0] = 0;
}

// ---------------------------------------------------------------- scatter points into cell order
__global__ __launch_bounds__(256) void scatter_kernel(
    const float4* __restrict__ p4, const int* __restrict__ pt_cell,
    const int* __restrict__ cell_start, int* __restrict__ cursor,
    float4* __restrict__ sp4, int* __restrict__ sidx) {
  int tid = blockIdx.x * blockDim.x + threadIdx.x;
  if (tid < N_PTS) {
    int c = pt_cell[tid];
    int pos = cell_start[c] + atomicAdd(&cursor[c], 1);
    sp4[pos] = p4[tid];
    sidx[pos] = tid;
  }
}

// ---------------------------------------------------------------- exact grid KNN: one wave per cell
__global__ __launch_bounds__(256) void knn_grid(
    const float4* __restrict__ sp4, const int* __restrict__ sidx,
    const int* __restrict__ cell_start, int* __restrict__ nbr) {
  const int cell = blockIdx.x * 4 + (threadIdx.x >> 6);
  const int lane = threadIdx.x & 63;
  const int hcx = cell & 7, hcy = (cell >> 3) & 7, hcz = cell >> 6;
  const int cs = cell_start[cell], ce = cell_start[cell + 1];

  const int ax0 = max(hcx - 1, 0), ax1 = min(hcx + 1, GDIM - 1);
  const int ay0 = max(hcy - 1, 0), ay1 = min(hcy + 1, GDIM - 1);
  const int az0 = max(hcz - 1, 0), az1 = min(hcz + 1, GDIM - 1);

  for (int base = cs; base < ce; base += 64) {
    const int my = base + lane;
    const bool active = my < ce;
    const int ld = active ? my : cs;
    const float4 pi = sp4[ld];
    const int orig = sidx[ld];

    unsigned long long ak[16];
    #pragma unroll
    for (int s = 0; s < 16; ++s) ak[s] = ~0ULL;

    // phase A: clamped 3x3x3 neighborhood (exact keys)
    for (int cz = az0; cz <= az1; ++cz)
      for (int cy = ay0; cy <= ay1; ++cy)
        for (int cx = ax0; cx <= ax1; ++cx) {
          int cc = (cz * GDIM + cy) * GDIM + cx;
          int s0 = cell_start[cc], e0 = cell_start[cc + 1];
          for (int k = s0; k < e0; ++k) {
            float4 q = sp4[k];
            float d = dist2(pi, q);
            chain_insert(ak, make_key(d, sidx[k]));
          }
        }

    // phase B: expand to all cells intersecting the 16-NN ball (edge/corner cases)
    float r;
    if (ak[0] == ~0ULL) {
      r = 1e9f;  // fewer than 16 candidates found: exact full-grid fallback
    } else {
      unsigned int ord = (unsigned int)(ak[0] >> 32);
      unsigned int di = (ord & 0x80000000u) ? (ord ^ 0x80000000u) : ~ord;
      float d16 = __uint_as_float(di);
      r = sqrtf(fmaxf(d16, 0.f)) * 1.001f + 1e-4f;
    }
    int lx = active ? min(GDIM - 1, max(0, (int)floorf((pi.x - r) * GDIM))) : hcx;
    int ux = active ? min(GDIM - 1, max(0, (int)floorf((pi.x + r) * GDIM))) : hcx;
    int ly = active ? min(GDIM - 1, max(0, (int)floorf((pi.y - r) * GDIM))) : hcy;
    int uy = active ? min(GDIM - 1, max(0, (int)floorf((pi.y + r) * GDIM))) : hcy;
    int lz = active ? min(GDIM - 1, max(0, (int)floorf((pi.z - r) * GDIM))) : hcz;
    int uz = active ? min(GDIM - 1, max(0, (int)floorf((pi.z + r) * GDIM))) : hcz;
    #pragma unroll
    for (int m = 32; m >= 1; m >>= 1) {
      lx = min(lx, __shfl_xor(lx, m));
      ly = min(ly, __shfl_xor(ly, m));
      lz = min(lz, __shfl_xor(lz, m));
      ux = max(ux, __shfl_xor(ux, m));
      uy = max(uy, __shfl_xor(uy, m));
      uz = max(uz, __shfl_xor(uz, m));
    }
    for (int cz = lz; cz <= uz; ++cz)
      for (int cy = ly; cy <= uy; ++cy)
        for (int cx = lx; cx <= ux; ++cx) {
          if (cx >= ax0 && cx <= ax1 && cy >= ay0 && cy <= ay1 && cz >= az0 && cz <= az1)
            continue;  // already scanned in phase A
          int cc = (cz * GDIM + cy) * GDIM + cx;
          int s0 = cell_start[cc], e0 = cell_start[cc + 1];
          for (int k = s0; k < e0; ++k) {
            float4 q = sp4[k];
            float d = dist2(pi, q);
            chain_insert(ak, make_key(d, sidx[k]));
          }
        }

    if (active) {
      #pragma unroll
      for (int s = 0; s < 16; ++s) nbr[orig * NSAMP + s] = (int)(ak[s] & 0xFFFFFFFFu);
    }
  }
}

// ---------------------------------------------------------------- qkv gemm: bf16 MFMA, no LDS
__global__ __launch_bounds__(256) void gemm_qkv_mfma(
    const __hip_bfloat16* __restrict__ x_bf, const __hip_bfloat16* __restrict__ Bp,
    const float* __restrict__ biasp, __hip_bfloat16* __restrict__ xqkv) {
  const int w = threadIdx.x >> 6;
  const int lane = threadIdx.x & 63;
  const int gw = blockIdx.x * 4 + w;          // 1536 waves: 128 m-tiles x 12 n-tiles
  const int m0 = (gw & 127) * 64;
  const int nt4 = (gw >> 7) * 4;
  const int n = lane & 15, q = lane >> 4;

  f32x4 acc[4][4];
  #pragma unroll
  for (int mi = 0; mi < 4; ++mi)
    #pragma unroll
    for (int ni = 0; ni < 4; ++ni) acc[mi][ni] = (f32x4){0.f, 0.f, 0.f, 0.f};

  for (int k0 = 0; k0 < 256; k0 += 32) {
    bf16x8 af[4], bfr[4];
    #pragma unroll
    for (int mi = 0; mi < 4; ++mi)
      af[mi] = *(const bf16x8*)&x_bf[(size_t)(m0 + mi * 16 + n) * 256 + k0 + q * 8];
    #pragma unroll
    for (int ni = 0; ni < 4; ++ni)
      bfr[ni] = *(const bf16x8*)&Bp[(size_t)(nt4 + ni) * 4096 + (k0 >> 3) * 128 + q * 128 + n * 8];
    #pragma unroll
    for (int mi = 0; mi < 4; ++mi)
      #pragma unroll
      for (int ni = 0; ni < 4; ++ni)
        acc[mi][ni] = __builtin_amdgcn_mfma_f32_16x16x32_bf16(af[mi], bfr[ni], acc[mi][ni], 0, 0, 0);
  }
  #pragma unroll
  for (int ni = 0; ni < 4; ++ni) {
    int col = (nt4 + ni) * 16 + n;
    float b = biasp[col];
    #pragma unroll
    for (int mi = 0; mi < 4; ++mi)
      #pragma unroll
      for (int r = 0; r < 4; ++r)
        xqkv[(size_t)(m0 + mi * 16 + q * 4 + r) * 768 + col] = __float2bfloat16(acc[mi][ni][r] + b);
  }
}

// ---------------------------------------------------------------- fused per-point transform (bf16 gather + MFMA linear_w)
__global__ __launch_bounds__(256) void fused_pt(
    const float* __restrict__ p, const __hip_bfloat16* __restrict__ xqkv,
    const int* __restrict__ nbr,
    const float* __restrict__ pw1, const float* __restrict__ pb1,
    const float* __restrict__ pbng, const float* __restrict__ pbnb,
    const float* __restrict__ pbnm, const float* __restrict__ pbnv,
    const float* __restrict__ pw2, const float* __restrict__ pb2,
    const float* __restrict__ bn1g, const float* __restrict__ bn1b,
    const float* __restrict__ bn1m, const float* __restrict__ bn1v,
    const __hip_bfloat16* __restrict__ l1wp, const float* __restrict__ l1b,
    const float* __restrict__ bn2g, const float* __restrict__ bn2b,
    const float* __restrict__ bn2m, const float* __restrict__ bn2v,
    const __hip_bfloat16* __restrict__ l2wp, const float* __restrict__ l2b,
    float* __restrict__ out) {
  __shared__ __align__(16) __hip_bfloat16 a_s[NSAMP][264];
  __shared__ __align__(16) __hip_bfloat16 h1_s[NSAMP][40];
  __shared__ float w_s[NSAMP][33];
  __shared__ float q3_s[NSAMP][4];
  __shared__ int jn[NSAMP];

  const int i = blockIdx.x;
  const int tid = threadIdx.x;

  if (tid < NSAMP) {
    int j = nbr[i * NSAMP + tid];
    jn[tid] = j;
    float rx = p[j * 3 + 0] - p[i * 3 + 0];
    float ry = p[j * 3 + 1] - p[i * 3 + 1];
    float rz = p[j * 3 + 2] - p[i * 3 + 2];
    #pragma unroll
    for (int c3 = 0; c3 < 3; ++c3) {
      float t = rx * pw1[0 * 3 + c3] + ry * pw1[1 * 3 + c3] + rz * pw1[2 * 3 + c3] + pb1[c3];
      t = (t - pbnm[c3]) * rsqrtf(pbnv[c3] + EPSBN) * pbng[c3] + pbnb[c3];
      q3_s[tid][c3] = fmaxf(t, 0.f);
    }
  }
  __syncthreads();

  const int c = tid;
  const float xq_c = __bfloat162float(xqkv[(size_t)i * 768 + c]);
  const float s1 = bn1g[c] * rsqrtf(bn1v[c] + EPSBN);
  const float o1 = bn1b[c] - bn1m[c] * s1;
  const float w2c0 = pw2[c], w2c1 = pw2[256 + c], w2c2 = pw2[512 + c];
  const float pb2c = pb2[c];
  #pragma unroll
  for (int t = 0; t < NSAMP; ++t) {
    int j = jn[t];
    float prv = q3_s[t][0] * w2c0 + q3_s[t][1] * w2c1 + q3_s[t][2] * w2c2 + pb2c;
    float xkv = __bfloat162float(xqkv[(size_t)j * 768 + 256 + c]);
    float r = xkv - xq_c + prv;
    a_s[t][c] = __float2bfloat16(fmaxf(r * s1 + o1, 0.f));
  }
  __syncthreads();

  const int wv_ = tid >> 6;
  const int lane = tid & 63;
  const int nn = lane & 15, q = lane >> 4;
  if (wv_ < 2) {
    f32x4 acc = {0.f, 0.f, 0.f, 0.f};
    #pragma unroll
    for (int k0 = 0; k0 < 256; k0 += 32) {
      bf16x8 a = *(const bf16x8*)&a_s[nn][k0 + q * 8];
      bf16x8 b = *(const bf16x8*)&l1wp[wv_ * 4096 + (k0 >> 3) * 128 + q * 128 + nn * 8];
      acc = __builtin_amdgcn_mfma_f32_16x16x32_bf16(a, b, acc, 0, 0, 0);
    }
    int h = wv_ * 16 + nn;
    float s2 = bn2g[h] * rsqrtf(bn2v[h] + EPSBN);
    float o2 = bn2b[h] - bn2m[h] * s2;
    float l1bh = l1b[h];
    #pragma unroll
    for (int r = 0; r < 4; ++r)
      h1_s[q * 4 + r][h] = __float2bfloat16(fmaxf((acc[r] + l1bh) * s2 + o2, 0.f));
  }
  __syncthreads();

  if (wv_ < 2) {
    bf16x8 a = *(const bf16x8*)&h1_s[nn][q * 8];
    bf16x8 b = *(const bf16x8*)&l2wp[wv_ * 512 + q * 128 + nn * 8];
    f32x4 z = {0.f, 0.f, 0.f, 0.f};
    f32x4 d = __builtin_amdgcn_mfma_f32_16x16x32_bf16(a, b, z, 0, 0, 0);
    int h = wv_ * 16 + nn;
    float l2bh = l2b[h];
    #pragma unroll
    for (int r = 0; r < 4; ++r) w_s[q * 4 + r][h] = d[r] + l2bh;
  }
  __syncthreads();

  if (tid < H_W) {
    int h = tid;
    float m = -1e30f;
    #pragma unroll
    for (int t = 0; t < NSAMP; ++t) m = fmaxf(m, w_s[t][h]);
    float e[NSAMP];
    float ssum = 0.f;
    #pragma unroll
    for (int t = 0; t < NSAMP; ++t) { e[t] = __expf(w_s[t][h] - m); ssum += e[t]; }
    float inv = 1.f / ssum;
    #pragma unroll
    for (int t = 0; t < NSAMP; ++t) w_s[t][h] = e[t] * inv;
  }
  __syncthreads();

  const int h = c & 31;
  float acc6 = 0.f;
  #pragma unroll
  for (int t = 0; t < NSAMP; ++t) {
    int j = jn[t];
    float xv = __bfloat162float(xqkv[(size_t)j * 768 + 512 + c]);
    float prv = q3_s[t][0] * w2c0 + q3_s[t][1] * w2c1 + q3_s[t][2] * w2c2 + pb2c;
    acc6 += (xv + prv) * w_s[t][h];
  }
  out[(size_t)i * OUT_C + c] = acc6;
}

// ---------------------------------------------------------------- launch
extern "C" void kernel_launch(void* const* d_in, const int* in_sizes, int n_in,
                              void* d_out, int out_size, void* d_ws, size_t ws_size,
                              hipStream_t stream) {
  const float* p    = (const float*)d_in[0];
  const float* x    = (const float*)d_in[1];
  const float* wq   = (const float*)d_in[2];
  const float* bq   = (const float*)d_in[3];
  const float* wk   = (const float*)d_in[4];
  const float* bk   = (const float*)d_in[5];
  const float* wv   = (const float*)d_in[6];
  const float* bv   = (const float*)d_in[7];
  const float* pw1  = (const float*)d_in[8];
  const float* pb1  = (const float*)d_in[9];
  const float* pbng = (const float*)d_in[10];
  const float* pbnb = (const float*)d_in[11];
  const float* pbnm = (const float*)d_in[12];
  const float* pbnv = (const float*)d_in[13];
  const float* pw2  = (const float*)d_in[14];
  const float* pb2  = (const float*)d_in[15];
  const float* bn1g = (const float*)d_in[16];
  const float* bn1b = (const float*)d_in[17];
  const float* bn1m = (const float*)d_in[18];
  const float* bn1v = (const float*)d_in[19];
  const float* l1w  = (const float*)d_in[20];
  const float* l1b  = (const float*)d_in[21];
  const float* bn2g = (const float*)d_in[22];
  const float* bn2b = (const float*)d_in[23];
  const float* bn2m = (const float*)d_in[24];
  const float* bn2v = (const float*)d_in[25];
  const float* l2w  = (const float*)d_in[26];
  const float* l2b  = (const float*)d_in[27];
  float* out = (float*)d_out;

  char* ws = (char*)d_ws;
  float4* p4       = (float4*)(ws + 0x000000);           // 128 KB
  float*  biasp    = (float*)(ws + 0x040000);            // 3 KB
  int*    hist     = (int*)(ws + 0x042000);              // 2 KB
  int*    cursor   = (int*)(ws + 0x042800);              // 2 KB
  int*    cell_st  = (int*)(ws + 0x043000);              // 2052 B
  int*    pt_cell  = (int*)(ws + 0x044000);              // 32 KB
  float4* sp4      = (float4*)(ws + 0x050000);           // 128 KB
  int*    sidx     = (int*)(ws + 0x070000);              // 32 KB
  __hip_bfloat16* l1wp = (__hip_bfloat16*)(ws + 0x080000);  // 16 KB
  __hip_bfloat16* l2wp = (__hip_bfloat16*)(ws + 0x084000);  // 2 KB
  int*    nbr      = (int*)(ws + 0x090000);              // 512 KB
  __hip_bfloat16* Bp   = (__hip_bfloat16*)(ws + 0x110000);  // 384 KB
  __hip_bfloat16* x_bf = (__hip_bfloat16*)(ws + 0x170000);  // 4 MB
  __hip_bfloat16* xqkv = (__hip_bfloat16*)(ws + 0x570000);  // 12 MB (ends ~17.5 MB)

  hipMemsetAsync(ws + 0x042000, 0, 0x1000, stream);  // hist + cursor
  prep_kernel<<<dim3(N_PTS), dim3(256), 0, stream>>>(
      p, x, wq, wk, wv, bq, bk, bv, l1w, l2w, p4, Bp, biasp, x_bf, l1wp, l2wp,
      hist, pt_cell);
  scan512<<<dim3(1), dim3(NCELL), 0, stream>>>(hist, cell_st);
  scatter_kernel<<<dim3(32), dim3(256), 0, stream>>>(p4, pt_cell, cell_st, cursor, sp4, sidx);
  gemm_qkv_mfma<<<dim3(384), dim3(256), 0, stream>>>(x_bf, Bp, biasp, xqkv);
  knn_grid<<<dim3(NCELL / 4), dim3(256), 0, stream>>>(sp4, sidx, cell_st, nbr);
  fused_pt<<<dim3(N_PTS), dim3(256), 0, stream>>>(
      p, xqkv, nbr, pw1, pb1, pbng, pbnb, pbnm, pbnv, pw2, pb2,
      bn1g, bn1b, bn1m, bn1v, l1wp, l1b, bn2g, bn2b, bn2m, bn2v, l2wp, l2b, out);
}

// Round 6
// 232.318 us; speedup vs baseline: 4.0764x; 1.2906x over previous
//
#include <hip/hip_runtime.h>
#include <hip/hip_bf16.h>
#include <math.h>

#define N_PTS 8192
#define C_IN  256
#define OUT_C 256
#define NSAMP 16
#define H_W   32
#define EPSBN 1e-5f
#define GDIM  8
#define NCELL (GDIM * GDIM * GDIM)
#define CAPC  1280

typedef short bf16x8 __attribute__((ext_vector_type(8)));
typedef float f32x4  __attribute__((ext_vector_type(4)));

// EXACT arithmetic from the passing rounds: plain expression, default
// compiler contraction, shared by all scans. Do NOT change the rounding.
__device__ __forceinline__ float dist2(const float4 a, const float4 b) {
  float dot = a.x * b.x + a.y * b.y + a.z * b.z;
  return a.w + b.w - 2.0f * dot;
}

__device__ __forceinline__ unsigned long long make_key(float d, int j) {
  unsigned int di = __float_as_uint(d);
  unsigned int ord = ((int)di >= 0) ? (di ^ 0x80000000u) : ~di;
  return ((unsigned long long)ord << 32) | (unsigned int)j;
}

// ak sorted DESCENDING: ak[0] = largest kept (16th-smallest overall)
__device__ __forceinline__ void chain_insert(unsigned long long (&ak)[16], unsigned long long key) {
  if (key < ak[0]) {
    #pragma unroll
    for (int s = 0; s < 15; ++s) {
      unsigned long long mn = ak[s] < key ? ak[s] : key;
      unsigned long long nx = ak[s + 1];
      ak[s] = nx > mn ? nx : mn;
    }
    ak[15] = ak[15] < key ? ak[15] : key;
  }
}

// ---------------------------------------------------------------- prep
__global__ __launch_bounds__(256) void prep_kernel(
    const float* __restrict__ p, const float* __restrict__ x,
    const float* __restrict__ wq, const float* __restrict__ wk, const float* __restrict__ wv,
    const float* __restrict__ bq, const float* __restrict__ bk, const float* __restrict__ bv,
    const float* __restrict__ l1w, const float* __restrict__ l2w,
    float4* __restrict__ p4, __hip_bfloat16* __restrict__ Bp, float* __restrict__ biasp,
    __hip_bfloat16* __restrict__ x_bf,
    __hip_bfloat16* __restrict__ l1wp, __hip_bfloat16* __restrict__ l2wp,
    int* __restrict__ hist, int* __restrict__ pt_cell) {
  int tid = blockIdx.x * blockDim.x + threadIdx.x;
  if (tid < 48 * 32 * 16 * 8) {
    int kj = tid & 7, n = (tid >> 3) & 15, kb = (tid >> 7) & 31, nt = tid >> 12;
    int k = kb * 8 + kj, col = nt * 16 + n;
    float v;
    if (col < 256)      v = wq[k * 256 + col];
    else if (col < 512) v = wk[k * 256 + (col - 256)];
    else                v = wv[k * 256 + (col - 512)];
    Bp[tid] = __float2bfloat16(v);
  }
  if (tid < 768) {
    biasp[tid] = tid < 256 ? bq[tid] : (tid < 512 ? bk[tid - 256] : bv[tid - 512]);
  }
  if (tid < 8192) {
    int kj = tid & 7, n = (tid >> 3) & 15, kb = (tid >> 7) & 31, nt = (tid >> 12) & 1;
    int k = kb * 8 + kj, col = nt * 16 + n;
    l1wp[tid] = __float2bfloat16(l1w[k * 32 + col]);
  }
  if (tid < 1024) {
    int kj = tid & 7, n = (tid >> 3) & 15, kb = (tid >> 7) & 3, nt = (tid >> 9) & 1;
    int k = kb * 8 + kj, col = nt * 16 + n;
    l2wp[tid] = __float2bfloat16(l2w[k * 32 + col]);
  }
  if (tid < N_PTS) {
    float px = p[tid * 3 + 0], py = p[tid * 3 + 1], pz = p[tid * 3 + 2];
    float sq = px * px;
    sq += py * py;
    sq += pz * pz;
    p4[tid] = make_float4(px, py, pz, sq);
    int cx = min(GDIM - 1, max(0, (int)(px * GDIM)));
    int cy = min(GDIM - 1, max(0, (int)(py * GDIM)));
    int cz = min(GDIM - 1, max(0, (int)(pz * GDIM)));
    int cell = (cz * GDIM + cy) * GDIM + cx;
    pt_cell[tid] = cell;
    atomicAdd(&hist[cell], 1);
  }
  if (tid < N_PTS * C_IN) x_bf[tid] = __float2bfloat16(x[tid]);
}

// ---------------------------------------------------------------- grid scan
__global__ __launch_bounds__(512) void scan512(const int* __restrict__ hist, int* __restrict__ cell_start) {
  __shared__ int buf[NCELL];
  int t = threadIdx.x;
  buf[t] = hist[t];
  __syncthreads();
  for (int off = 1; off < NCELL; off <<= 1) {
    int add = (t >= off) ? buf[t - off] : 0;
    __syncthreads();
    buf[t] += add;
    __syncthreads();
  }
  cell_start[t + 1] = buf[t];
  if (t == 0) cell_start[0] = 0;
}

// ---------------------------------------------------------------- scatter
__global__ __launch_bounds__(256) void scatter_kernel(
    const float4* __restrict__ p4, const int* __restrict__ pt_cell,
    const int* __restrict__ cell_start, int* __restrict__ cursor,
    float4* __restrict__ sp4, int* __restrict__ sidx) {
  int tid = blockIdx.x * blockDim.x + threadIdx.x;
  if (tid < N_PTS) {
    int c = pt_cell[tid];
    int pos = cell_start[c] + atomicAdd(&cursor[c], 1);
    sp4[pos] = p4[tid];
    sidx[pos] = tid;
  }
}

// ---------------------------------------------------------------- exact grid KNN: one BLOCK per cell, slice-parallel
__global__ __launch_bounds__(256) void knn_grid(
    const float4* __restrict__ sp4, const int* __restrict__ sidx,
    const int* __restrict__ cell_start, int* __restrict__ nbr) {
  __shared__ float4 cpos[CAPC];
  __shared__ int    cidx[CAPC];
  __shared__ unsigned long long chains[16][16][16];  // [pt][slice][e], ascending
  __shared__ int cell_s0_s[27];
  __shared__ int pref_s[28];
  __shared__ int nc_s, total_s;

  const int cell = blockIdx.x;
  const int tid = threadIdx.x;
  const int hcx = cell & 7, hcy = (cell >> 3) & 7, hcz = cell >> 6;
  const int cs = cell_start[cell], ce = cell_start[cell + 1];

  const int ax0 = max(hcx - 1, 0), ax1 = min(hcx + 1, GDIM - 1);
  const int ay0 = max(hcy - 1, 0), ay1 = min(hcy + 1, GDIM - 1);
  const int az0 = max(hcz - 1, 0), az1 = min(hcz + 1, GDIM - 1);

  if (tid == 0) {
    int off = 0, m = 0;
    for (int cz = az0; cz <= az1; ++cz)
      for (int cy = ay0; cy <= ay1; ++cy)
        for (int cx = ax0; cx <= ax1; ++cx) {
          int cc = (cz * GDIM + cy) * GDIM + cx;
          cell_s0_s[m] = cell_start[cc];
          pref_s[m] = off;
          off += cell_start[cc + 1] - cell_start[cc];
          ++m;
        }
    pref_s[m] = off;
    nc_s = m;
    total_s = off;
  }
  __syncthreads();
  const int nc = nc_s, total = total_s;

  // stage candidates into LDS (coalesced per cell segment)
  for (int idx = tid; idx < total && idx < CAPC; idx += 256) {
    int c = 0;
    while (c + 1 < nc && pref_s[c + 1] <= idx) ++c;
    int g = cell_s0_s[c] + (idx - pref_s[c]);
    cpos[idx] = sp4[g];
    cidx[idx] = sidx[g];
  }
  __syncthreads();

  const int ptl = tid & 15, slice = tid >> 4;

  for (int p0 = cs; p0 < ce; p0 += 16) {
    const int np = min(16, ce - p0);
    const bool pok = ptl < np;
    float4 pi = make_float4(0.f, 0.f, 0.f, 0.f);
    int orig = 0;
    if (pok) { pi = sp4[p0 + ptl]; orig = sidx[p0 + ptl]; }

    unsigned long long ak[16];
    #pragma unroll
    for (int s = 0; s < 16; ++s) ak[s] = ~0ULL;

    if (pok) {
      for (int idx = slice; idx < total; idx += 16) {
        float4 q;
        int qi;
        if (idx < CAPC) { q = cpos[idx]; qi = cidx[idx]; }
        else {  // overflow path (exactness guard; ~never taken)
          int c = 0;
          while (c + 1 < nc && pref_s[c + 1] <= idx) ++c;
          int g = cell_s0_s[c] + (idx - pref_s[c]);
          q = sp4[g]; qi = sidx[g];
        }
        chain_insert(ak, make_key(dist2(pi, q), qi));
      }
    }
    #pragma unroll
    for (int s = 0; s < 16; ++s) chains[ptl][slice][s] = ak[15 - s];  // store ascending
    __syncthreads();

    // bitonic tree-merge of 16 sorted lists per point
    for (int step = 8; step >= 1; step >>= 1) {
      if (slice < step && pok) {
        unsigned long long A[16], B[16], t[16];
        #pragma unroll
        for (int s = 0; s < 16; ++s) { A[s] = chains[ptl][slice][s]; B[s] = chains[ptl][slice + step][s]; }
        #pragma unroll
        for (int s = 0; s < 16; ++s) t[s] = A[s] < B[15 - s] ? A[s] : B[15 - s];
        #pragma unroll
        for (int k = 8; k >= 1; k >>= 1) {
          #pragma unroll
          for (int s = 0; s < 16; ++s) {
            if (!(s & k)) {
              unsigned long long lo = t[s] < t[s | k] ? t[s] : t[s | k];
              unsigned long long hi = t[s] < t[s | k] ? t[s | k] : t[s];
              t[s] = lo; t[s | k] = hi;
            }
          }
        }
        #pragma unroll
        for (int s = 0; s < 16; ++s) chains[ptl][slice][s] = t[s];
      }
      __syncthreads();
    }

    // phase B: ball-vs-clamped-box exactness guard + output (slice 0)
    if (slice == 0 && pok) {
      unsigned long long akm[16];
      #pragma unroll
      for (int s = 0; s < 16; ++s) akm[s] = chains[ptl][0][15 - s];  // back to descending
      float r;
      if (akm[0] == ~0ULL) {
        r = 1e9f;
      } else {
        unsigned int ord = (unsigned int)(akm[0] >> 32);
        unsigned int di = (ord & 0x80000000u) ? (ord ^ 0x80000000u) : ~ord;
        float d16 = __uint_as_float(di);
        r = sqrtf(fmaxf(d16, 0.f)) * 1.001f + 1e-4f;
      }
      int lx = (int)fminf(fmaxf(floorf((pi.x - r) * GDIM), 0.f), (float)(GDIM - 1));
      int ux = (int)fminf(fmaxf(floorf((pi.x + r) * GDIM), 0.f), (float)(GDIM - 1));
      int ly = (int)fminf(fmaxf(floorf((pi.y - r) * GDIM), 0.f), (float)(GDIM - 1));
      int uy = (int)fminf(fmaxf(floorf((pi.y + r) * GDIM), 0.f), (float)(GDIM - 1));
      int lz = (int)fminf(fmaxf(floorf((pi.z - r) * GDIM), 0.f), (float)(GDIM - 1));
      int uz = (int)fminf(fmaxf(floorf((pi.z + r) * GDIM), 0.f), (float)(GDIM - 1));
      if (lx < ax0 || ux > ax1 || ly < ay0 || uy > ay1 || lz < az0 || uz > az1) {
        for (int cz = lz; cz <= uz; ++cz)
          for (int cy = ly; cy <= uy; ++cy)
            for (int cx = lx; cx <= ux; ++cx) {
              if (cx >= ax0 && cx <= ax1 && cy >= ay0 && cy <= ay1 && cz >= az0 && cz <= az1)
                continue;
              int cc = (cz * GDIM + cy) * GDIM + cx;
              int s0 = cell_start[cc], e0 = cell_start[cc + 1];
              for (int k = s0; k < e0; ++k) {
                float4 q = sp4[k];
                chain_insert(akm, make_key(dist2(pi, q), sidx[k]));
              }
            }
      }
      #pragma unroll
      for (int s = 0; s < 16; ++s) nbr[orig * NSAMP + s] = (int)(akm[s] & 0xFFFFFFFFu);
    }
    __syncthreads();  // chains reused by next chunk
  }
}

// ---------------------------------------------------------------- qkv gemm: bf16 MFMA, no LDS
__global__ __launch_bounds__(256) void gemm_qkv_mfma(
    const __hip_bfloat16* __restrict__ x_bf, const __hip_bfloat16* __restrict__ Bp,
    const float* __restrict__ biasp, __hip_bfloat16* __restrict__ xqkv) {
  const int w = threadIdx.x >> 6;
  const int lane = threadIdx.x & 63;
  const int gw = blockIdx.x * 4 + w;
  const int m0 = (gw & 127) * 64;
  const int nt4 = (gw >> 7) * 4;
  const int n = lane & 15, q = lane >> 4;

  f32x4 acc[4][4];
  #pragma unroll
  for (int mi = 0; mi < 4; ++mi)
    #pragma unroll
    for (int ni = 0; ni < 4; ++ni) acc[mi][ni] = (f32x4){0.f, 0.f, 0.f, 0.f};

  for (int k0 = 0; k0 < 256; k0 += 32) {
    bf16x8 af[4], bfr[4];
    #pragma unroll
    for (int mi = 0; mi < 4; ++mi)
      af[mi] = *(const bf16x8*)&x_bf[(size_t)(m0 + mi * 16 + n) * 256 + k0 + q * 8];
    #pragma unroll
    for (int ni = 0; ni < 4; ++ni)
      bfr[ni] = *(const bf16x8*)&Bp[(size_t)(nt4 + ni) * 4096 + (k0 >> 3) * 128 + q * 128 + n * 8];
    #pragma unroll
    for (int mi = 0; mi < 4; ++mi)
      #pragma unroll
      for (int ni = 0; ni < 4; ++ni)
        acc[mi][ni] = __builtin_amdgcn_mfma_f32_16x16x32_bf16(af[mi], bfr[ni], acc[mi][ni], 0, 0, 0);
  }
  #pragma unroll
  for (int ni = 0; ni < 4; ++ni) {
    int col = (nt4 + ni) * 16 + n;
    float b = biasp[col];
    #pragma unroll
    for (int mi = 0; mi < 4; ++mi)
      #pragma unroll
      for (int r = 0; r < 4; ++r)
        xqkv[(size_t)(m0 + mi * 16 + q * 4 + r) * 768 + col] = __float2bfloat16(acc[mi][ni][r] + b);
  }
}

// ---------------------------------------------------------------- fused per-point transform
__global__ __launch_bounds__(256) void fused_pt(
    const float* __restrict__ p, const __hip_bfloat16* __restrict__ xqkv,
    const int* __restrict__ nbr,
    const float* __restrict__ pw1, const float* __restrict__ pb1,
    const float* __restrict__ pbng, const float* __restrict__ pbnb,
    const float* __restrict__ pbnm, const float* __restrict__ pbnv,
    const float* __restrict__ pw2, const float* __restrict__ pb2,
    const float* __restrict__ bn1g, const float* __restrict__ bn1b,
    const float* __restrict__ bn1m, const float* __restrict__ bn1v,
    const __hip_bfloat16* __restrict__ l1wp, const float* __restrict__ l1b,
    const float* __restrict__ bn2g, const float* __restrict__ bn2b,
    const float* __restrict__ bn2m, const float* __restrict__ bn2v,
    const __hip_bfloat16* __restrict__ l2wp, const float* __restrict__ l2b,
    float* __restrict__ out) {
  __shared__ __align__(16) __hip_bfloat16 a_s[NSAMP][264];
  __shared__ __align__(16) __hip_bfloat16 h1_s[NSAMP][40];
  __shared__ float w_s[NSAMP][33];
  __shared__ float q3_s[NSAMP][4];
  __shared__ int jn[NSAMP];

  const int i = blockIdx.x;
  const int tid = threadIdx.x;

  if (tid < NSAMP) {
    int j = nbr[i * NSAMP + tid];
    jn[tid] = j;
    float rx = p[j * 3 + 0] - p[i * 3 + 0];
    float ry = p[j * 3 + 1] - p[i * 3 + 1];
    float rz = p[j * 3 + 2] - p[i * 3 + 2];
    #pragma unroll
    for (int c3 = 0; c3 < 3; ++c3) {
      float t = rx * pw1[0 * 3 + c3] + ry * pw1[1 * 3 + c3] + rz * pw1[2 * 3 + c3] + pb1[c3];
      t = (t - pbnm[c3]) * rsqrtf(pbnv[c3] + EPSBN) * pbng[c3] + pbnb[c3];
      q3_s[tid][c3] = fmaxf(t, 0.f);
    }
  }
  __syncthreads();

  const int c = tid;
  const float xq_c = __bfloat162float(xqkv[(size_t)i * 768 + c]);
  const float s1 = bn1g[c] * rsqrtf(bn1v[c] + EPSBN);
  const float o1 = bn1b[c] - bn1m[c] * s1;
  const float w2c0 = pw2[c], w2c1 = pw2[256 + c], w2c2 = pw2[512 + c];
  const float pb2c = pb2[c];
  #pragma unroll
  for (int t = 0; t < NSAMP; ++t) {
    int j = jn[t];
    float prv = q3_s[t][0] * w2c0 + q3_s[t][1] * w2c1 + q3_s[t][2] * w2c2 + pb2c;
    float xkv = __bfloat162float(xqkv[(size_t)j * 768 + 256 + c]);
    float r = xkv - xq_c + prv;
    a_s[t][c] = __float2bfloat16(fmaxf(r * s1 + o1, 0.f));
  }
  __syncthreads();

  const int wv_ = tid >> 6;
  const int lane = tid & 63;
  const int nn = lane & 15, q = lane >> 4;
  if (wv_ < 2) {
    f32x4 acc = {0.f, 0.f, 0.f, 0.f};
    #pragma unroll
    for (int k0 = 0; k0 < 256; k0 += 32) {
      bf16x8 a = *(const bf16x8*)&a_s[nn][k0 + q * 8];
      bf16x8 b = *(const bf16x8*)&l1wp[wv_ * 4096 + (k0 >> 3) * 128 + q * 128 + nn * 8];
      acc = __builtin_amdgcn_mfma_f32_16x16x32_bf16(a, b, acc, 0, 0, 0);
    }
    int h = wv_ * 16 + nn;
    float s2 = bn2g[h] * rsqrtf(bn2v[h] + EPSBN);
    float o2 = bn2b[h] - bn2m[h] * s2;
    float l1bh = l1b[h];
    #pragma unroll
    for (int r = 0; r < 4; ++r)
      h1_s[q * 4 + r][h] = __float2bfloat16(fmaxf((acc[r] + l1bh) * s2 + o2, 0.f));
  }
  __syncthreads();

  if (wv_ < 2) {
    bf16x8 a = *(const bf16x8*)&h1_s[nn][q * 8];
    bf16x8 b = *(const bf16x8*)&l2wp[wv_ * 512 + q * 128 + nn * 8];
    f32x4 z = {0.f, 0.f, 0.f, 0.f};
    f32x4 d = __builtin_amdgcn_mfma_f32_16x16x32_bf16(a, b, z, 0, 0, 0);
    int h = wv_ * 16 + nn;
    float l2bh = l2b[h];
    #pragma unroll
    for (int r = 0; r < 4; ++r) w_s[q * 4 + r][h] = d[r] + l2bh;
  }
  __syncthreads();

  if (tid < H_W) {
    int h = tid;
    float m = -1e30f;
    #pragma unroll
    for (int t = 0; t < NSAMP; ++t) m = fmaxf(m, w_s[t][h]);
    float e[NSAMP];
    float ssum = 0.f;
    #pragma unroll
    for (int t = 0; t < NSAMP; ++t) { e[t] = __expf(w_s[t][h] - m); ssum += e[t]; }
    float inv = 1.f / ssum;
    #pragma unroll
    for (int t = 0; t < NSAMP; ++t) w_s[t][h] = e[t] * inv;
  }
  __syncthreads();

  const int h = c & 31;
  float acc6 = 0.f;
  #pragma unroll
  for (int t = 0; t < NSAMP; ++t) {
    int j = jn[t];
    float xv = __bfloat162float(xqkv[(size_t)j * 768 + 512 + c]);
    float prv = q3_s[t][0] * w2c0 + q3_s[t][1] * w2c1 + q3_s[t][2] * w2c2 + pb2c;
    acc6 += (xv + prv) * w_s[t][h];
  }
  out[(size_t)i * OUT_C + c] = acc6;
}

// ---------------------------------------------------------------- launch
extern "C" void kernel_launch(void* const* d_in, const int* in_sizes, int n_in,
                              void* d_out, int out_size, void* d_ws, size_t ws_size,
                              hipStream_t stream) {
  const float* p    = (const float*)d_in[0];
  const float* x    = (const float*)d_in[1];
  const float* wq   = (const float*)d_in[2];
  const float* bq   = (const float*)d_in[3];
  const float* wk   = (const float*)d_in[4];
  const float* bk   = (const float*)d_in[5];
  const float* wv   = (const float*)d_in[6];
  const float* bv   = (const float*)d_in[7];
  const float* pw1  = (const float*)d_in[8];
  const float* pb1  = (const float*)d_in[9];
  const float* pbng = (const float*)d_in[10];
  const float* pbnb = (const float*)d_in[11];
  const float* pbnm = (const float*)d_in[12];
  const float* pbnv = (const float*)d_in[13];
  const float* pw2  = (const float*)d_in[14];
  const float* pb2  = (const float*)d_in[15];
  const float* bn1g = (const float*)d_in[16];
  const float* bn1b = (const float*)d_in[17];
  const float* bn1m = (const float*)d_in[18];
  const float* bn1v = (const float*)d_in[19];
  const float* l1w  = (const float*)d_in[20];
  const float* l1b  = (const float*)d_in[21];
  const float* bn2g = (const float*)d_in[22];
  const float* bn2b = (const float*)d_in[23];
  const float* bn2m = (const float*)d_in[24];
  const float* bn2v = (const float*)d_in[25];
  const float* l2w  = (const float*)d_in[26];
  const float* l2b  = (const float*)d_in[27];
  float* out = (float*)d_out;

  char* ws = (char*)d_ws;
  float4* p4       = (float4*)(ws + 0x000000);
  float*  biasp    = (float*)(ws + 0x040000);
  int*    hist     = (int*)(ws + 0x042000);
  int*    cursor   = (int*)(ws + 0x042800);
  int*    cell_st  = (int*)(ws + 0x043000);
  int*    pt_cell  = (int*)(ws + 0x044000);
  float4* sp4      = (float4*)(ws + 0x050000);
  int*    sidx     = (int*)(ws + 0x070000);
  __hip_bfloat16* l1wp = (__hip_bfloat16*)(ws + 0x080000);
  __hip_bfloat16* l2wp = (__hip_bfloat16*)(ws + 0x084000);
  int*    nbr      = (int*)(ws + 0x090000);
  __hip_bfloat16* Bp   = (__hip_bfloat16*)(ws + 0x110000);
  __hip_bfloat16* x_bf = (__hip_bfloat16*)(ws + 0x170000);
  __hip_bfloat16* xqkv = (__hip_bfloat16*)(ws + 0x570000);

  hipMemsetAsync(ws + 0x042000, 0, 0x1000, stream);  // hist + cursor
  prep_kernel<<<dim3(N_PTS), dim3(256), 0, stream>>>(
      p, x, wq, wk, wv, bq, bk, bv, l1w, l2w, p4, Bp, biasp, x_bf, l1wp, l2wp,
      hist, pt_cell);
  scan512<<<dim3(1), dim3(NCELL), 0, stream>>>(hist, cell_st);
  scatter_kernel<<<dim3(32), dim3(256), 0, stream>>>(p4, pt_cell, cell_st, cursor, sp4, sidx);
  gemm_qkv_mfma<<<dim3(384), dim3(256), 0, stream>>>(x_bf, Bp, biasp, xqkv);
  knn_grid<<<dim3(NCELL), dim3(256), 0, stream>>>(sp4, sidx, cell_st, nbr);
  fused_pt<<<dim3(N_PTS), dim3(256), 0, stream>>>(
      p, xqkv, nbr, pw1, pb1, pbng, pbnb, pbnm, pbnv, pw2, pb2,
      bn1g, bn1b, bn1m, bn1v, l1wp, l1b, bn2g, bn2b, bn2m, bn2v, l2wp, l2b, out);
}

// Round 7
// 221.825 us; speedup vs baseline: 4.2692x; 1.0473x over previous
//
#include <hip/hip_runtime.h>
#include <hip/hip_bf16.h>
#include <math.h>

#define N_PTS 8192
#define C_IN  256
#define OUT_C 256
#define NSAMP 16
#define H_W   32
#define EPSBN 1e-5f
#define GDIM  8
#define NCELL (GDIM * GDIM * GDIM)
#define CAPC  768

typedef short bf16x8 __attribute__((ext_vector_type(8)));
typedef float f32x4  __attribute__((ext_vector_type(4)));

// EXACT arithmetic from the passing rounds: plain expression, default
// compiler contraction, shared by all scans. Do NOT change the rounding.
__device__ __forceinline__ float dist2(const float4 a, const float4 b) {
  float dot = a.x * b.x + a.y * b.y + a.z * b.z;
  return a.w + b.w - 2.0f * dot;
}

__device__ __forceinline__ unsigned long long make_key(float d, int j) {
  unsigned int di = __float_as_uint(d);
  unsigned int ord = ((int)di >= 0) ? (di ^ 0x80000000u) : ~di;
  return ((unsigned long long)ord << 32) | (unsigned int)j;
}

// ak sorted DESCENDING: ak[0] = largest kept (16th-smallest overall)
__device__ __forceinline__ void chain_insert(unsigned long long (&ak)[16], unsigned long long key) {
  if (key < ak[0]) {
    #pragma unroll
    for (int s = 0; s < 15; ++s) {
      unsigned long long mn = ak[s] < key ? ak[s] : key;
      unsigned long long nx = ak[s + 1];
      ak[s] = nx > mn ? nx : mn;
    }
    ak[15] = ak[15] < key ? ak[15] : key;
  }
}

// Merge this lane's ascending top-16 list with lane^m's (bitonic); both lanes
// end with the identical merged ascending top-16. All lanes must execute.
__device__ __forceinline__ void merge16(unsigned long long (&A)[16], int m) {
  unsigned long long B[16], t[16];
  #pragma unroll
  for (int s = 0; s < 16; ++s) B[s] = __shfl_xor(A[s], m, 64);
  #pragma unroll
  for (int s = 0; s < 16; ++s) t[s] = A[s] < B[15 - s] ? A[s] : B[15 - s];
  #pragma unroll
  for (int k = 8; k >= 1; k >>= 1) {
    #pragma unroll
    for (int s = 0; s < 16; ++s) {
      if (!(s & k)) {
        unsigned long long lo = t[s] < t[s | k] ? t[s] : t[s | k];
        unsigned long long hi = t[s] < t[s | k] ? t[s | k] : t[s];
        t[s] = lo; t[s | k] = hi;
      }
    }
  }
  #pragma unroll
  for (int s = 0; s < 16; ++s) A[s] = t[s];
}

// ---------------------------------------------------------------- prep
__global__ __launch_bounds__(256) void prep_kernel(
    const float* __restrict__ p, const float* __restrict__ x,
    const float* __restrict__ wq, const float* __restrict__ wk, const float* __restrict__ wv,
    const float* __restrict__ bq, const float* __restrict__ bk, const float* __restrict__ bv,
    const float* __restrict__ l1w, const float* __restrict__ l2w,
    float4* __restrict__ p4, __hip_bfloat16* __restrict__ Bp, float* __restrict__ biasp,
    __hip_bfloat16* __restrict__ x_bf,
    __hip_bfloat16* __restrict__ l1wp, __hip_bfloat16* __restrict__ l2wp,
    int* __restrict__ hist, int* __restrict__ pt_cell) {
  int tid = blockIdx.x * blockDim.x + threadIdx.x;
  if (tid < 48 * 32 * 16 * 8) {
    int kj = tid & 7, n = (tid >> 3) & 15, kb = (tid >> 7) & 31, nt = tid >> 12;
    int k = kb * 8 + kj, col = nt * 16 + n;
    float v;
    if (col < 256)      v = wq[k * 256 + col];
    else if (col < 512) v = wk[k * 256 + (col - 256)];
    else                v = wv[k * 256 + (col - 512)];
    Bp[tid] = __float2bfloat16(v);
  }
  if (tid < 768) {
    biasp[tid] = tid < 256 ? bq[tid] : (tid < 512 ? bk[tid - 256] : bv[tid - 512]);
  }
  if (tid < 8192) {
    int kj = tid & 7, n = (tid >> 3) & 15, kb = (tid >> 7) & 31, nt = (tid >> 12) & 1;
    int k = kb * 8 + kj, col = nt * 16 + n;
    l1wp[tid] = __float2bfloat16(l1w[k * 32 + col]);
  }
  if (tid < 1024) {
    int kj = tid & 7, n = (tid >> 3) & 15, kb = (tid >> 7) & 3, nt = (tid >> 9) & 1;
    int k = kb * 8 + kj, col = nt * 16 + n;
    l2wp[tid] = __float2bfloat16(l2w[k * 32 + col]);
  }
  if (tid < N_PTS) {
    float px = p[tid * 3 + 0], py = p[tid * 3 + 1], pz = p[tid * 3 + 2];
    float sq = px * px;
    sq += py * py;
    sq += pz * pz;
    p4[tid] = make_float4(px, py, pz, sq);
    int cx = min(GDIM - 1, max(0, (int)(px * GDIM)));
    int cy = min(GDIM - 1, max(0, (int)(py * GDIM)));
    int cz = min(GDIM - 1, max(0, (int)(pz * GDIM)));
    int cell = (cz * GDIM + cy) * GDIM + cx;
    pt_cell[tid] = cell;
    atomicAdd(&hist[cell], 1);
  }
  if (tid < N_PTS * C_IN) x_bf[tid] = __float2bfloat16(x[tid]);
}

// ---------------------------------------------------------------- grid scan
__global__ __launch_bounds__(512) void scan512(const int* __restrict__ hist, int* __restrict__ cell_start) {
  __shared__ int buf[NCELL];
  int t = threadIdx.x;
  buf[t] = hist[t];
  __syncthreads();
  for (int off = 1; off < NCELL; off <<= 1) {
    int add = (t >= off) ? buf[t - off] : 0;
    __syncthreads();
    buf[t] += add;
    __syncthreads();
  }
  cell_start[t + 1] = buf[t];
  if (t == 0) cell_start[0] = 0;
}

// ---------------------------------------------------------------- scatter (also emits orig->sorted rank)
__global__ __launch_bounds__(256) void scatter_kernel(
    const float4* __restrict__ p4, const int* __restrict__ pt_cell,
    const int* __restrict__ cell_start, int* __restrict__ cursor,
    float4* __restrict__ sp4, int* __restrict__ sidx, int* __restrict__ rank) {
  int tid = blockIdx.x * blockDim.x + threadIdx.x;
  if (tid < N_PTS) {
    int c = pt_cell[tid];
    int pos = cell_start[c] + atomicAdd(&cursor[c], 1);
    sp4[pos] = p4[tid];
    sidx[pos] = tid;
    rank[tid] = pos;
  }
}

// ---------------------------------------------------------------- exact grid KNN: block/cell, shfl-merged chains
__global__ __launch_bounds__(256) void knn_grid(
    const float4* __restrict__ sp4, const int* __restrict__ sidx,
    const int* __restrict__ cell_start, int* __restrict__ nbr) {
  __shared__ float4 cpos[CAPC];
  __shared__ int    cidx[CAPC];
  __shared__ int cell_s0_s[27];
  __shared__ int pref_s[28];
  __shared__ int nc_s, total_s;

  const int cell = blockIdx.x;
  const int tid = threadIdx.x;
  const int hcx = cell & 7, hcy = (cell >> 3) & 7, hcz = cell >> 6;
  const int cs = cell_start[cell], ce = cell_start[cell + 1];

  const int ax0 = max(hcx - 1, 0), ax1 = min(hcx + 1, GDIM - 1);
  const int ay0 = max(hcy - 1, 0), ay1 = min(hcy + 1, GDIM - 1);
  const int az0 = max(hcz - 1, 0), az1 = min(hcz + 1, GDIM - 1);

  if (tid == 0) {
    int off = 0, m = 0;
    for (int cz = az0; cz <= az1; ++cz)
      for (int cy = ay0; cy <= ay1; ++cy)
        for (int cx = ax0; cx <= ax1; ++cx) {
          int cc = (cz * GDIM + cy) * GDIM + cx;
          cell_s0_s[m] = cell_start[cc];
          pref_s[m] = off;
          off += cell_start[cc + 1] - cell_start[cc];
          ++m;
        }
    pref_s[m] = off;
    nc_s = m;
    total_s = off;
  }
  __syncthreads();
  const int nc = nc_s, total = total_s;

  for (int idx = tid; idx < total && idx < CAPC; idx += 256) {
    int c = 0;
    while (c + 1 < nc && pref_s[c + 1] <= idx) ++c;
    int g = cell_s0_s[c] + (idx - pref_s[c]);
    cpos[idx] = sp4[g];
    cidx[idx] = sidx[g];
  }
  __syncthreads();

  // thread = ptl*16 + slice: a point's 16 slices are 16 consecutive lanes
  const int ptl = tid >> 4, slice = tid & 15;

  for (int p0 = cs; p0 < ce; p0 += 16) {
    const int np = min(16, ce - p0);
    const bool pok = ptl < np;
    const int ld = pok ? (p0 + ptl) : cs;
    const float4 pi = sp4[ld];
    const int orig = sidx[ld];

    unsigned long long ak[16];
    #pragma unroll
    for (int s = 0; s < 16; ++s) ak[s] = ~0ULL;

    for (int idx = slice; idx < total; idx += 16) {
      float4 q;
      int qi;
      if (idx < CAPC) { q = cpos[idx]; qi = cidx[idx]; }
      else {  // overflow exactness guard (~never taken)
        int c = 0;
        while (c + 1 < nc && pref_s[c + 1] <= idx) ++c;
        int g = cell_s0_s[c] + (idx - pref_s[c]);
        q = sp4[g]; qi = sidx[g];
      }
      chain_insert(ak, make_key(dist2(pi, q), qi));
    }

    unsigned long long asc[16];
    #pragma unroll
    for (int s = 0; s < 16; ++s) asc[s] = ak[15 - s];
    merge16(asc, 1);
    merge16(asc, 2);
    merge16(asc, 4);
    merge16(asc, 8);

    if (slice == 0 && pok) {
      unsigned long long akm[16];
      #pragma unroll
      for (int s = 0; s < 16; ++s) akm[s] = asc[15 - s];  // descending
      float r;
      if (akm[0] == ~0ULL) {
        r = 1e9f;
      } else {
        unsigned int ord = (unsigned int)(akm[0] >> 32);
        unsigned int di = (ord & 0x80000000u) ? (ord ^ 0x80000000u) : ~ord;
        float d16 = __uint_as_float(di);
        r = sqrtf(fmaxf(d16, 0.f)) * 1.001f + 1e-4f;
      }
      int lx = (int)fminf(fmaxf(floorf((pi.x - r) * GDIM), 0.f), (float)(GDIM - 1));
      int ux = (int)fminf(fmaxf(floorf((pi.x + r) * GDIM), 0.f), (float)(GDIM - 1));
      int ly = (int)fminf(fmaxf(floorf((pi.y - r) * GDIM), 0.f), (float)(GDIM - 1));
      int uy = (int)fminf(fmaxf(floorf((pi.y + r) * GDIM), 0.f), (float)(GDIM - 1));
      int lz = (int)fminf(fmaxf(floorf((pi.z - r) * GDIM), 0.f), (float)(GDIM - 1));
      int uz = (int)fminf(fmaxf(floorf((pi.z + r) * GDIM), 0.f), (float)(GDIM - 1));
      if (lx < ax0 || ux > ax1 || ly < ay0 || uy > ay1 || lz < az0 || uz > az1) {
        for (int cz = lz; cz <= uz; ++cz)
          for (int cy = ly; cy <= uy; ++cy)
            for (int cx = lx; cx <= ux; ++cx) {
              if (cx >= ax0 && cx <= ax1 && cy >= ay0 && cy <= ay1 && cz >= az0 && cz <= az1)
                continue;
              int cc = (cz * GDIM + cy) * GDIM + cx;
              int s0 = cell_start[cc], e0 = cell_start[cc + 1];
              for (int k = s0; k < e0; ++k) {
                float4 q = sp4[k];
                chain_insert(akm, make_key(dist2(pi, q), sidx[k]));
              }
            }
      }
      #pragma unroll
      for (int s = 0; s < 16; ++s) nbr[orig * NSAMP + s] = (int)(akm[s] & 0xFFFFFFFFu);
    }
  }
}

// ---------------------------------------------------------------- qkv gemm: bf16 MFMA, output rows in SORTED order
__global__ __launch_bounds__(256) void gemm_qkv_mfma(
    const __hip_bfloat16* __restrict__ x_bf, const __hip_bfloat16* __restrict__ Bp,
    const float* __restrict__ biasp, const int* __restrict__ rank,
    __hip_bfloat16* __restrict__ xqkv) {
  const int w = threadIdx.x >> 6;
  const int lane = threadIdx.x & 63;
  const int gw = blockIdx.x * 4 + w;
  const int m0 = (gw & 127) * 64;
  const int nt4 = (gw >> 7) * 4;
  const int n = lane & 15, q = lane >> 4;

  f32x4 acc[4][4];
  #pragma unroll
  for (int mi = 0; mi < 4; ++mi)
    #pragma unroll
    for (int ni = 0; ni < 4; ++ni) acc[mi][ni] = (f32x4){0.f, 0.f, 0.f, 0.f};

  for (int k0 = 0; k0 < 256; k0 += 32) {
    bf16x8 af[4], bfr[4];
    #pragma unroll
    for (int mi = 0; mi < 4; ++mi)
      af[mi] = *(const bf16x8*)&x_bf[(size_t)(m0 + mi * 16 + n) * 256 + k0 + q * 8];
    #pragma unroll
    for (int ni = 0; ni < 4; ++ni)
      bfr[ni] = *(const bf16x8*)&Bp[(size_t)(nt4 + ni) * 4096 + (k0 >> 3) * 128 + q * 128 + n * 8];
    #pragma unroll
    for (int mi = 0; mi < 4; ++mi)
      #pragma unroll
      for (int ni = 0; ni < 4; ++ni)
        acc[mi][ni] = __builtin_amdgcn_mfma_f32_16x16x32_bf16(af[mi], bfr[ni], acc[mi][ni], 0, 0, 0);
  }
  float bcol[4];
  #pragma unroll
  for (int ni = 0; ni < 4; ++ni) bcol[ni] = biasp[(nt4 + ni) * 16 + n];
  #pragma unroll
  for (int mi = 0; mi < 4; ++mi)
    #pragma unroll
    for (int r = 0; r < 4; ++r) {
      int row = m0 + mi * 16 + q * 4 + r;
      size_t srow = (size_t)rank[row];
      #pragma unroll
      for (int ni = 0; ni < 4; ++ni)
        xqkv[srow * 768 + (nt4 + ni) * 16 + n] = __float2bfloat16(acc[mi][ni][r] + bcol[ni]);
    }
}

// ---------------------------------------------------------------- fused per-point transform (sorted-space gathers)
__global__ __launch_bounds__(256) void fused_pt(
    const float4* __restrict__ sp4, const int* __restrict__ sidx, const int* __restrict__ rank,
    const __hip_bfloat16* __restrict__ xqkv, const int* __restrict__ nbr,
    const float* __restrict__ pw1, const float* __restrict__ pb1,
    const float* __restrict__ pbng, const float* __restrict__ pbnb,
    const float* __restrict__ pbnm, const float* __restrict__ pbnv,
    const float* __restrict__ pw2, const float* __restrict__ pb2,
    const float* __restrict__ bn1g, const float* __restrict__ bn1b,
    const float* __restrict__ bn1m, const float* __restrict__ bn1v,
    const __hip_bfloat16* __restrict__ l1wp, const float* __restrict__ l1b,
    const float* __restrict__ bn2g, const float* __restrict__ bn2b,
    const float* __restrict__ bn2m, const float* __restrict__ bn2v,
    const __hip_bfloat16* __restrict__ l2wp, const float* __restrict__ l2b,
    float* __restrict__ out) {
  __shared__ __align__(16) __hip_bfloat16 a_s[NSAMP][264];
  __shared__ __align__(16) __hip_bfloat16 h1_s[NSAMP][40];
  __shared__ float w_s[NSAMP][33];
  __shared__ float q3_s[NSAMP][4];
  __shared__ int jn[NSAMP];

  const int b = blockIdx.x;            // sorted position
  const int i = sidx[b];               // original index
  const int tid = threadIdx.x;

  if (tid < NSAMP) {
    int j = nbr[i * NSAMP + tid];      // orig neighbor id (exact R6 selection)
    int k = rank[j];                   // sorted row
    jn[tid] = k;
    float4 pj = sp4[k];
    float4 pc = sp4[b];
    float rx = pj.x - pc.x;
    float ry = pj.y - pc.y;
    float rz = pj.z - pc.z;
    #pragma unroll
    for (int c3 = 0; c3 < 3; ++c3) {
      float t = rx * pw1[0 * 3 + c3] + ry * pw1[1 * 3 + c3] + rz * pw1[2 * 3 + c3] + pb1[c3];
      t = (t - pbnm[c3]) * rsqrtf(pbnv[c3] + EPSBN) * pbng[c3] + pbnb[c3];
      q3_s[tid][c3] = fmaxf(t, 0.f);
    }
  }
  __syncthreads();

  const int c = tid;
  const float xq_c = __bfloat162float(xqkv[(size_t)b * 768 + c]);
  const float s1 = bn1g[c] * rsqrtf(bn1v[c] + EPSBN);
  const float o1 = bn1b[c] - bn1m[c] * s1;
  const float w2c0 = pw2[c], w2c1 = pw2[256 + c], w2c2 = pw2[512 + c];
  const float pb2c = pb2[c];
  #pragma unroll
  for (int t = 0; t < NSAMP; ++t) {
    int k = jn[t];
    float prv = q3_s[t][0] * w2c0 + q3_s[t][1] * w2c1 + q3_s[t][2] * w2c2 + pb2c;
    float xkv = __bfloat162float(xqkv[(size_t)k * 768 + 256 + c]);
    float r = xkv - xq_c + prv;
    a_s[t][c] = __float2bfloat16(fmaxf(r * s1 + o1, 0.f));
  }
  __syncthreads();

  const int wv_ = tid >> 6;
  const int lane = tid & 63;
  const int nn = lane & 15, q = lane >> 4;
  if (wv_ < 2) {
    f32x4 acc = {0.f, 0.f, 0.f, 0.f};
    #pragma unroll
    for (int k0 = 0; k0 < 256; k0 += 32) {
      bf16x8 a = *(const bf16x8*)&a_s[nn][k0 + q * 8];
      bf16x8 bb = *(const bf16x8*)&l1wp[wv_ * 4096 + (k0 >> 3) * 128 + q * 128 + nn * 8];
      acc = __builtin_amdgcn_mfma_f32_16x16x32_bf16(a, bb, acc, 0, 0, 0);
    }
    int h = wv_ * 16 + nn;
    float s2 = bn2g[h] * rsqrtf(bn2v[h] + EPSBN);
    float o2 = bn2b[h] - bn2m[h] * s2;
    float l1bh = l1b[h];
    #pragma unroll
    for (int r = 0; r < 4; ++r)
      h1_s[q * 4 + r][h] = __float2bfloat16(fmaxf((acc[r] + l1bh) * s2 + o2, 0.f));
  }
  __syncthreads();

  if (wv_ < 2) {
    bf16x8 a = *(const bf16x8*)&h1_s[nn][q * 8];
    bf16x8 bb = *(const bf16x8*)&l2wp[wv_ * 512 + q * 128 + nn * 8];
    f32x4 z = {0.f, 0.f, 0.f, 0.f};
    f32x4 d = __builtin_amdgcn_mfma_f32_16x16x32_bf16(a, bb, z, 0, 0, 0);
    int h = wv_ * 16 + nn;
    float l2bh = l2b[h];
    #pragma unroll
    for (int r = 0; r < 4; ++r) w_s[q * 4 + r][h] = d[r] + l2bh;
  }
  __syncthreads();

  if (tid < H_W) {
    int h = tid;
    float m = -1e30f;
    #pragma unroll
    for (int t = 0; t < NSAMP; ++t) m = fmaxf(m, w_s[t][h]);
    float e[NSAMP];
    float ssum = 0.f;
    #pragma unroll
    for (int t = 0; t < NSAMP; ++t) { e[t] = __expf(w_s[t][h] - m); ssum += e[t]; }
    float inv = 1.f / ssum;
    #pragma unroll
    for (int t = 0; t < NSAMP; ++t) w_s[t][h] = e[t] * inv;
  }
  __syncthreads();

  const int h = c & 31;
  float acc6 = 0.f;
  #pragma unroll
  for (int t = 0; t < NSAMP; ++t) {
    int k = jn[t];
    float xv = __bfloat162float(xqkv[(size_t)k * 768 + 512 + c]);
    float prv = q3_s[t][0] * w2c0 + q3_s[t][1] * w2c1 + q3_s[t][2] * w2c2 + pb2c;
    acc6 += (xv + prv) * w_s[t][h];
  }
  out[(size_t)i * OUT_C + c] = acc6;
}

// ---------------------------------------------------------------- launch
extern "C" void kernel_launch(void* const* d_in, const int* in_sizes, int n_in,
                              void* d_out, int out_size, void* d_ws, size_t ws_size,
                              hipStream_t stream) {
  const float* p    = (const float*)d_in[0];
  const float* x    = (const float*)d_in[1];
  const float* wq   = (const float*)d_in[2];
  const float* bq   = (const float*)d_in[3];
  const float* wk   = (const float*)d_in[4];
  const float* bk   = (const float*)d_in[5];
  const float* wv   = (const float*)d_in[6];
  const float* bv   = (const float*)d_in[7];
  const float* pw1  = (const float*)d_in[8];
  const float* pb1  = (const float*)d_in[9];
  const float* pbng = (const float*)d_in[10];
  const float* pbnb = (const float*)d_in[11];
  const float* pbnm = (const float*)d_in[12];
  const float* pbnv = (const float*)d_in[13];
  const float* pw2  = (const float*)d_in[14];
  const float* pb2  = (const float*)d_in[15];
  const float* bn1g = (const float*)d_in[16];
  const float* bn1b = (const float*)d_in[17];
  const float* bn1m = (const float*)d_in[18];
  const float* bn1v = (const float*)d_in[19];
  const float* l1w  = (const float*)d_in[20];
  const float* l1b  = (const float*)d_in[21];
  const float* bn2g = (const float*)d_in[22];
  const float* bn2b = (const float*)d_in[23];
  const float* bn2m = (const float*)d_in[24];
  const float* bn2v = (const float*)d_in[25];
  const float* l2w  = (const float*)d_in[26];
  const float* l2b  = (const float*)d_in[27];
  float* out = (float*)d_out;

  char* ws = (char*)d_ws;
  float4* p4       = (float4*)(ws + 0x000000);
  float*  biasp    = (float*)(ws + 0x040000);
  int*    hist     = (int*)(ws + 0x042000);
  int*    cursor   = (int*)(ws + 0x042800);
  int*    cell_st  = (int*)(ws + 0x043000);
  int*    pt_cell  = (int*)(ws + 0x044000);
  float4* sp4      = (float4*)(ws + 0x050000);
  int*    sidx     = (int*)(ws + 0x070000);
  __hip_bfloat16* l1wp = (__hip_bfloat16*)(ws + 0x080000);
  __hip_bfloat16* l2wp = (__hip_bfloat16*)(ws + 0x084000);
  int*    rank     = (int*)(ws + 0x088000);
  int*    nbr      = (int*)(ws + 0x090000);
  __hip_bfloat16* Bp   = (__hip_bfloat16*)(ws + 0x110000);
  __hip_bfloat16* x_bf = (__hip_bfloat16*)(ws + 0x170000);
  __hip_bfloat16* xqkv = (__hip_bfloat16*)(ws + 0x570000);

  hipMemsetAsync(ws + 0x042000, 0, 0x1000, stream);  // hist + cursor
  prep_kernel<<<dim3(N_PTS), dim3(256), 0, stream>>>(
      p, x, wq, wk, wv, bq, bk, bv, l1w, l2w, p4, Bp, biasp, x_bf, l1wp, l2wp,
      hist, pt_cell);
  scan512<<<dim3(1), dim3(NCELL), 0, stream>>>(hist, cell_st);
  scatter_kernel<<<dim3(32), dim3(256), 0, stream>>>(p4, pt_cell, cell_st, cursor, sp4, sidx, rank);
  gemm_qkv_mfma<<<dim3(384), dim3(256), 0, stream>>>(x_bf, Bp, biasp, rank, xqkv);
  knn_grid<<<dim3(NCELL), dim3(256), 0, stream>>>(sp4, sidx, cell_st, nbr);
  fused_pt<<<dim3(N_PTS), dim3(256), 0, stream>>>(
      sp4, sidx, rank, xqkv, nbr, pw1, pb1, pbng, pbnb, pbnm, pbnv, pw2, pb2,
      bn1g, bn1b, bn1m, bn1v, l1wp, l1b, bn2g, bn2b, bn2m, bn2v, l2wp, l2b, out);
}